// Round 5
// baseline (351.293 us; speedup 1.0000x reference)
//
#include <hip/hip_runtime.h>
#include <hip/hip_bf16.h>

typedef __hip_bfloat16 bf16;
typedef __attribute__((ext_vector_type(8))) short bf16x8;
typedef __attribute__((ext_vector_type(4))) float f32x4;

constexpr int NN = 50000;           // nodes
constexpr int NE = 800000;          // edges (without self loops)
constexpr int NT = NE + NN;         // edges incl self loops
constexpr int NNB  = (NN + 127)/128; // 391 fill buckets (128 dsts each)
constexpr int NPART = 8;             // XCD partitions (blockIdx & 7)
constexpr int PCAP = 512;            // slots per (bucket, partition); mean 256, 16 sigma

// flag-selected load: f32 storage vs bf16 storage
__device__ __forceinline__ float cvt(const void* p, long long i, int f32){
  return f32 ? ((const float*)p)[i] : __bfloat162float(((const bf16*)p)[i]);
}
// bf16 <-> f32 (RNE pack)
__device__ __forceinline__ unsigned short f2bf(float f){
  unsigned u = __float_as_uint(f);
  u += 0x7fffu + ((u >> 16) & 1);
  return (unsigned short)(u >> 16);
}
__device__ __forceinline__ float bflo(unsigned p){ return __uint_as_float(p << 16); }
__device__ __forceinline__ float bfhi(unsigned p){ return __uint_as_float(p & 0xffff0000u); }
__device__ __forceinline__ unsigned packbf(float a, float b){
  return (unsigned)f2bf(a) | ((unsigned)f2bf(b) << 16);
}
// monotone float<->uint key for atomicMax
__device__ __forceinline__ unsigned f2key(float f){
  unsigned u = __float_as_uint(f);
  return (u & 0x80000000u) ? ~u : (u | 0x80000000u);
}
__device__ __forceinline__ float key2f(unsigned k){
  unsigned u = (k & 0x80000000u) ? (k & 0x7fffffffu) : ~k;
  return __uint_as_float(u);
}

struct SrcPtrs { const void* p[12]; };
// Weight conversion (blocks 0-11: f32 copies; block 0 publishes flag)
// + MFMA fragmentation (blocks 12-15): W -> hi/lo bf16 in lane order
// + zero blocks (16-23): clear SKA + bcur (replaces hipMemsetAsync dispatch)
__global__ void k_cvtall(SrcPtrs sp, float* __restrict__ Wc,
                         unsigned short* __restrict__ Wf, int* __restrict__ flag,
                         unsigned* __restrict__ zero0){
  const int sz[12]  = {8192,64,4096,64,8192,128,128,128,8192,64,64,32};
  const int off[12] = {0,8192,8256,12352,12416,20608,20736,20864,20992,29184,29248,29312};
  int tid = threadIdx.x;
  int b = blockIdx.x;
  if(b >= 16){
    constexpr int ZN = 128 + NPART*NNB*16;   // SKA + bcur dwords
    for(int i = (b-16)*256 + tid; i < ZN; i += 8*256) zero0[i] = 0u;
    return;
  }
  __shared__ int bad;
  if(tid == 0) bad = 0;
  __syncthreads();
  const unsigned short* q = (const unsigned short*)sp.p[0];   // W1, >=16KB either dtype
  int local = 0;
  for(int i = tid; i < 8192; i += 256){
    int e = (q[i] >> 7) & 0xFF;
    if(e >= 0xC0) local = 1;
  }
  if(local) atomicOr(&bad, 1);
  __syncthreads();
  int f = bad;
  if(b == 0 && tid == 0) *flag = f;
  if(b < 12){
    const void* src = sp.p[b];
    float* dst = Wc + off[b];
    int n = sz[b];
    for(int i = tid; i < n; i += 256) dst[i] = cvt(src, i, f);
  } else {
    int g = b - 12;
    const int KK[4]   = {128, 64, 64, 128};
    const int NNo[4]  = {64, 64, 128, 64};
    const int srcI[4] = {0, 2, 4, 8};            // W1, W2, Wg1, Wg2 in sp.p
    const int foff[4] = {0, 16384, 24576, 40960};
    int K = KK[g], N = NNo[g], KF = K/32;
    const void* src = sp.p[srcI[g]];
    unsigned short* dh = Wf + foff[g];
    unsigned short* dl = dh + K*N;
    int tot = K*N;
    for(int idx = tid; idx < tot; idx += 256){
      int i = idx & 7, lane = (idx >> 3) & 63, fr = idx >> 9;
      int kf = fr % KF, nf = fr / KF;
      int k = kf*32 + ((lane >> 4) << 3) + i;
      int n = nf*16 + (lane & 15);
      float w = cvt(src, (long long)k*N + n, f);
      unsigned short h = f2bf(w);
      dh[idx] = h;
      dl[idx] = f2bf(w - __uint_as_float((unsigned)h << 16));
    }
  }
}

// ---------------- CSR build: XCD-partitioned bin -> bucket-local scatter ----------------
__global__ void k_bin(const int* __restrict__ ei, int* __restrict__ bcur,
                      unsigned* __restrict__ tmp){
  int e = blockIdx.x*256 + threadIdx.x;
  int p = blockIdx.x & (NPART-1);
  if(e < NE){
    int dst = ei[NE + e];
    int src = ei[e];
    int b = dst >> 7;
    int pos = atomicAdd(&bcur[(p*NNB + b)*16], 1);
    if(pos < PCAP) tmp[((size_t)(b*NPART + p) << 9) + pos] = (unsigned)src | ((unsigned)(dst & 127) << 16);
  }
}
__global__ void k_scatter(const int* __restrict__ bcur,
                          const unsigned* __restrict__ tmp, int* __restrict__ rowptr,
                          int* __restrict__ rowend, float* __restrict__ dinv,
                          unsigned short* __restrict__ srcidx16){
  __shared__ int hist[128];
  __shared__ int lcur[128];
  __shared__ int sh[2][128];
  __shared__ int red[256];
  int b = blockIdx.x;
  int dst0 = b << 7;
  int nd = min(128, NN - dst0);
  int tid = threadIdx.x;
  int partial = 0;
  for(int i = tid; i < b*NPART; i += 256){
    int b2 = i >> 3, p = i & 7;
    partial += bcur[(p*NNB + b2)*16];
  }
  red[tid] = partial;
  if(tid < 128) hist[tid] = 0;
  __syncthreads();
  for(int off = 128; off; off >>= 1){
    if(tid < off) red[tid] += red[tid + off];
    __syncthreads();
  }
  int base = red[0] + (b << 7);
  for(int p = 0; p < NPART; p++){
    int cnt = min(bcur[(p*NNB + b)*16], PCAP);
    const unsigned* tp = tmp + ((size_t)(b*NPART + p) << 9);
    for(int i = tid; i < cnt; i += 256) atomicAdd(&hist[tp[i] >> 16], 1);
  }
  __syncthreads();
  int c = (tid < 128) ? hist[tid] + 1 : 0;     // +1 self loop
  if(tid < 128) sh[0][tid] = c;
  __syncthreads();
  int cur = 0;
  for(int off = 1; off < 128; off <<= 1){
    int nxt = cur^1;
    if(tid < 128){
      int v = sh[cur][tid];
      if(tid >= off) v += sh[cur][tid-off];
      sh[nxt][tid] = v;
    }
    __syncthreads();
    cur = nxt;
  }
  if(tid < nd){
    int rp = base + sh[cur][tid] - c;
    int d = dst0 + tid;
    rowptr[d] = rp;
    srcidx16[rp] = (unsigned short)d;
    rowend[d] = rp + c;
    dinv[d] = rsqrtf((float)c);
    lcur[tid] = rp + 1;
  }
  __syncthreads();
  for(int p = 0; p < NPART; p++){
    int cnt = min(bcur[(p*NNB + b)*16], PCAP);
    const unsigned* tp = tmp + ((size_t)(b*NPART + p) << 9);
    for(int i = tid; i < cnt; i += 256){
      unsigned v = tp[i];
      int pos = atomicAdd(&lcur[v >> 16], 1);
      srcidx16[pos] = (unsigned short)(v & 0xffffu);
    }
  }
}

// ---------------- MFMA dense layers ----------------
template<int KIN, int KOUT, bool SCALE, int PACKC, int MODE>
__global__ void k_mfma(const void* __restrict__ X, const unsigned short* __restrict__ Wh,
                       const unsigned short* __restrict__ Wl,
                       const float* __restrict__ dinv, void* __restrict__ out,
                       const float* __restrict__ asrc, const float* __restrict__ adst,
                       float* __restrict__ sS, float* __restrict__ sD,
                       unsigned* __restrict__ ska, const int* __restrict__ flag){
  constexpr int KF = KIN/32;
  constexpr int NF = KOUT/16;
  constexpr int PITCH = KOUT + 1;
  __shared__ float Cl[64*PITCH];
  __shared__ unsigned skey[2];
  int tid = threadIdx.x;
  if(PACKC > 0 && tid < 2) skey[tid] = 0;
  int wv = tid >> 6, lane = tid & 63;
  int lr = lane >> 4, lc = lane & 15;
  int row0 = blockIdx.x*64;
  int arow = row0 + wv*16 + lc;
  if(arow >= NN) arow = NN - 1;                  // clamp: results discarded
  int f = (MODE == 1) ? *flag : 0;
  const char* xb = (const char*)X;
  f32x4 acc[NF];
#pragma unroll
  for(int nf = 0; nf < NF; nf++) acc[nf] = (f32x4){0.f,0.f,0.f,0.f};
#pragma unroll
  for(int kf = 0; kf < KF; kf++){
    bf16x8 a;
    if(MODE == 1 && f){
      const float* xf = (const float*)xb + (size_t)arow*KIN + kf*32 + lr*8;
      float4 u = *(const float4*)xf;
      float4 v = *(const float4*)(xf + 4);
      a[0]=(short)f2bf(u.x); a[1]=(short)f2bf(u.y); a[2]=(short)f2bf(u.z); a[3]=(short)f2bf(u.w);
      a[4]=(short)f2bf(v.x); a[5]=(short)f2bf(v.y); a[6]=(short)f2bf(v.z); a[7]=(short)f2bf(v.w);
    } else {
      a = *(const bf16x8*)(xb + (size_t)arow*(KIN*2) + kf*64 + lr*16);
    }
#pragma unroll
    for(int nf = 0; nf < NF; nf++){
      int fr = nf*KF + kf;
      bf16x8 wh = *(const bf16x8*)((const short*)Wh + (fr << 9) + (lane << 3));
      bf16x8 wl = *(const bf16x8*)((const short*)Wl + (fr << 9) + (lane << 3));
      acc[nf] = __builtin_amdgcn_mfma_f32_16x16x32_bf16(a, wh, acc[nf], 0, 0, 0);
      acc[nf] = __builtin_amdgcn_mfma_f32_16x16x32_bf16(a, wl, acc[nf], 0, 0, 0);
    }
  }
#pragma unroll
  for(int nf = 0; nf < NF; nf++)
#pragma unroll
    for(int r = 0; r < 4; r++)
      Cl[(wv*16 + lr*4 + r)*PITCH + nf*16 + lc] = acc[nf][r];
  __syncthreads();
  int row = tid >> 2, q = tid & 3;
  int grow = row0 + row;
  bool valid = grow < NN;
  const float* cr = &Cl[row*PITCH];
  if constexpr (PACKC == 0){
    float s = SCALE ? (valid ? dinv[grow] : 0.0f) : 1.0f;
    unsigned ov[8];
#pragma unroll
    for(int j = 0; j < 8; j++)
      ov[j] = packbf(cr[q*16 + 2*j]*s, cr[q*16 + 2*j + 1]*s);
    if(valid){
      unsigned* op = (unsigned*)out + (size_t)grow*(KOUT/2) + q*8;
      *(uint4*)op       = make_uint4(ov[0],ov[1],ov[2],ov[3]);
      *(uint4*)(op + 4) = make_uint4(ov[4],ov[5],ov[6],ov[7]);
    }
  } else {
    constexpr int C = PACKC;
    constexpr int CT = C/4;                     // cols per thread
    float s0=0.f, d0=0.f, s1=0.f, d1=0.f;
    unsigned ov[CT];
#pragma unroll
    for(int j = 0; j < CT; j++){
      int c = q*CT + j;
      float a = cr[c], bb = cr[C + c];
      ov[j] = packbf(a, bb);
      s0 += a*asrc[c];      d0 += a*adst[c];
      s1 += bb*asrc[C + c]; d1 += bb*adst[C + c];
    }
    if(valid){
      unsigned* op = (unsigned*)out + (size_t)grow*C + q*CT;
#pragma unroll
      for(int j4 = 0; j4 < CT/4; j4++)
        *(uint4*)(op + 4*j4) = make_uint4(ov[4*j4],ov[4*j4+1],ov[4*j4+2],ov[4*j4+3]);
    }
    s0 += __shfl_xor(s0,1); s0 += __shfl_xor(s0,2);
    d0 += __shfl_xor(d0,1); d0 += __shfl_xor(d0,2);
    s1 += __shfl_xor(s1,1); s1 += __shfl_xor(s1,2);
    d1 += __shfl_xor(d1,1); d1 += __shfl_xor(d1,2);
    if(valid && q == 0){
      *(float2*)(sS + 2*grow) = make_float2(s0, s1);
      *(float2*)(sD + 2*grow) = make_float2(d0, d1);
      atomicMax(&skey[0], f2key(s0));
      atomicMax(&skey[1], f2key(s1));
    }
    __syncthreads();
    if(tid < 2) atomicMax(&ska[tid*32 + (blockIdx.x & 31)], skey[tid]);
  }
}

// ---------------- gather aggregations ----------------
// GCN: 4 nodes PER WAVE (MLP: ~12 row-loads in flight). 8 lanes/edge.
// Per-node math order identical to 1-node version -> bit-identical results.
__global__ void k_gcn_gather(const int* __restrict__ rowptr, const int* __restrict__ rowend,
                             const unsigned short* __restrict__ srcidx16, const float* __restrict__ dinv,
                             const unsigned* __restrict__ Au32, const float* __restrict__ bias,
                             unsigned* __restrict__ B){
  int wid = threadIdx.x >> 6, lane = threadIdx.x & 63;
  int n0 = (blockIdx.x*4 + wid)*4;
  if(n0 >= NN) return;
  int o = lane >> 3, c4 = lane & 7;
  int s0[4], ne[4], src[4];
  float acc[4][8];
#pragma unroll
  for(int i = 0; i < 4; i++){
    int n = min(n0 + i, NN-1);
    s0[i] = rowptr[n]; ne[i] = rowend[n] - s0[i];
    if(n0 + i >= NN) ne[i] = 0;
#pragma unroll
    for(int c = 0; c < 8; c++) acc[i][c] = 0.f;
  }
#pragma unroll
  for(int i = 0; i < 4; i++)
    src[i] = (lane < ne[i]) ? (int)srcidx16[s0[i] + lane] : -1;
#pragma unroll
  for(int i = 0; i < 4; i++){
#pragma unroll
    for(int j = 0; j < 8; j++){
      if(j*8 >= ne[i]) break;
      int sb = __shfl(src[i], 8*j + o);
      if(sb >= 0){
        uint4 p = *(const uint4*)(Au32 + (size_t)sb*32 + c4*4);
        acc[i][0] += bflo(p.x); acc[i][1] += bfhi(p.x);
        acc[i][2] += bflo(p.y); acc[i][3] += bfhi(p.y);
        acc[i][4] += bflo(p.z); acc[i][5] += bfhi(p.z);
        acc[i][6] += bflo(p.w); acc[i][7] += bfhi(p.w);
      }
    }
  }
  // rare long rows (ne > 64)
#pragma unroll
  for(int i = 0; i < 4; i++){
    for(int base = 64; base < ne[i]; base += 64){
      int my = base + lane;
      int s = (my < ne[i]) ? (int)srcidx16[s0[i] + my] : -1;
      int iters = (min(64, ne[i] - base) + 7) >> 3;
      for(int j = 0; j < iters; j++){
        int sb = __shfl(s, 8*j + o);
        if(sb >= 0){
          uint4 p = *(const uint4*)(Au32 + (size_t)sb*32 + c4*4);
          acc[i][0] += bflo(p.x); acc[i][1] += bfhi(p.x);
          acc[i][2] += bflo(p.y); acc[i][3] += bfhi(p.y);
          acc[i][4] += bflo(p.z); acc[i][5] += bfhi(p.z);
          acc[i][6] += bflo(p.w); acc[i][7] += bfhi(p.w);
        }
      }
    }
  }
#pragma unroll
  for(int i = 0; i < 4; i++)
#pragma unroll
    for(int off = 8; off <= 32; off <<= 1){
      acc[i][0] += __shfl_xor(acc[i][0], off); acc[i][1] += __shfl_xor(acc[i][1], off);
      acc[i][2] += __shfl_xor(acc[i][2], off); acc[i][3] += __shfl_xor(acc[i][3], off);
      acc[i][4] += __shfl_xor(acc[i][4], off); acc[i][5] += __shfl_xor(acc[i][5], off);
      acc[i][6] += __shfl_xor(acc[i][6], off); acc[i][7] += __shfl_xor(acc[i][7], off);
    }
  if(o == 0){
    int cb = 8*c4;
#pragma unroll
    for(int i = 0; i < 4; i++){
      int n = n0 + i;
      if(n >= NN) break;
      float dn = dinv[n];
      uint4 r;
      r.x = packbf(fmaxf(acc[i][0]*dn + bias[cb+0], 0.0f), fmaxf(acc[i][1]*dn + bias[cb+1], 0.0f));
      r.y = packbf(fmaxf(acc[i][2]*dn + bias[cb+2], 0.0f), fmaxf(acc[i][3]*dn + bias[cb+3], 0.0f));
      r.z = packbf(fmaxf(acc[i][4]*dn + bias[cb+4], 0.0f), fmaxf(acc[i][5]*dn + bias[cb+5], 0.0f));
      r.w = packbf(fmaxf(acc[i][6]*dn + bias[cb+6], 0.0f), fmaxf(acc[i][7]*dn + bias[cb+7], 0.0f));
      *(uint4*)(B + (size_t)n*32 + c4*4) = r;
    }
  }
}

// per-wave reduction of the 32-slot spread max keys
__device__ __forceinline__ void ska_max2(const unsigned* __restrict__ ska, int lane,
                                         float& m0, float& m1){
  unsigned kk = ska[lane];
#pragma unroll
  for(int off = 1; off <= 16; off <<= 1) kk = max(kk, __shfl_xor(kk, off));
  m0 = key2f(__shfl(kk, 0));
  m1 = key2f(__shfl(kk, 32));
}

// GAT1 (heads=2, C=64, concat): 2 nodes per wave; 16 lanes/edge. Writes bf16 B (128 cols).
__global__ void k_gat1_gather(const int* __restrict__ rowptr, const int* __restrict__ rowend,
                              const unsigned short* __restrict__ srcidx16, const float* __restrict__ sS,
                              const float* __restrict__ sD, const unsigned* __restrict__ Ab,
                              const float* __restrict__ bias, unsigned* __restrict__ B,
                              const unsigned* __restrict__ ska){
  int wid = threadIdx.x >> 6, lane = threadIdx.x & 63;
  int n0 = (blockIdx.x*4 + wid)*2;
  if(n0 >= NN) return;
  float g0, g1;
  ska_max2(ska, lane, g0, g1);
  int q = lane >> 4, c4 = lane & 15;
  int s0[2], ne[2], src[2];
  float d0[2], d1[2], m0[2], m1[2], w0[2], w1[2];
  float z0[2] = {0.f,0.f}, z1[2] = {0.f,0.f};
  float ab[2][4], ac[2][4];
#pragma unroll
  for(int i = 0; i < 2; i++){
    int n = min(n0 + i, NN-1);
    s0[i] = rowptr[n]; ne[i] = rowend[n] - s0[i];
    if(n0 + i >= NN) ne[i] = 0;
    d0[i] = sD[n*2]; d1[i] = sD[n*2+1];
    float t0 = g0 + d0[i];  m0[i] = t0 > 0.0f ? t0 : 0.2f*t0;
    float t1 = g1 + d1[i];  m1[i] = t1 > 0.0f ? t1 : 0.2f*t1;
#pragma unroll
    for(int c = 0; c < 4; c++){ ab[i][c] = 0.f; ac[i][c] = 0.f; }
  }
#pragma unroll
  for(int i = 0; i < 2; i++){
    src[i] = 0; w0[i] = 0.f; w1[i] = 0.f;
    if(lane < ne[i]){
      src[i] = (int)srcidx16[s0[i] + lane];
      float2 sv = *(const float2*)(sS + src[i]*2);
      float e0 = sv.x + d0[i]; e0 = e0 > 0.0f ? e0 : 0.2f*e0;
      float e1 = sv.y + d1[i]; e1 = e1 > 0.0f ? e1 : 0.2f*e1;
      w0[i] = __expf(e0 - m0[i]); w1[i] = __expf(e1 - m1[i]);
      z0[i] += w0[i]; z1[i] += w1[i];
    }
  }
#pragma unroll
  for(int i = 0; i < 2; i++){
#pragma unroll
    for(int j = 0; j < 16; j++){
      if(4*j >= ne[i]) break;
      int idx = 4*j + q;
      int sb = __shfl(src[i], idx);
      float a0 = __shfl(w0[i], idx), a1 = __shfl(w1[i], idx);
      uint4 p = *(const uint4*)(Ab + (size_t)sb*64 + c4*4);
      ab[i][0] += bflo(p.x)*a0; ac[i][0] += bfhi(p.x)*a1;
      ab[i][1] += bflo(p.y)*a0; ac[i][1] += bfhi(p.y)*a1;
      ab[i][2] += bflo(p.z)*a0; ac[i][2] += bfhi(p.z)*a1;
      ab[i][3] += bflo(p.w)*a0; ac[i][3] += bfhi(p.w)*a1;
    }
  }
  // rare long rows
#pragma unroll
  for(int i = 0; i < 2; i++){
    for(int base = 64; base < ne[i]; base += 64){
      int my = base + lane;
      int s = 0; float u0 = 0.f, u1 = 0.f;
      if(my < ne[i]){
        s = (int)srcidx16[s0[i] + my];
        float2 sv = *(const float2*)(sS + s*2);
        float e0 = sv.x + d0[i]; e0 = e0 > 0.0f ? e0 : 0.2f*e0;
        float e1 = sv.y + d1[i]; e1 = e1 > 0.0f ? e1 : 0.2f*e1;
        u0 = __expf(e0 - m0[i]); u1 = __expf(e1 - m1[i]);
        z0[i] += u0; z1[i] += u1;
      }
      int iters = (min(64, ne[i] - base) + 3) >> 2;
      for(int j = 0; j < iters; j++){
        int idx = 4*j + q;
        int sb = __shfl(s, idx);
        float a0 = __shfl(u0, idx), a1 = __shfl(u1, idx);
        uint4 p = *(const uint4*)(Ab + (size_t)sb*64 + c4*4);
        ab[i][0] += bflo(p.x)*a0; ac[i][0] += bfhi(p.x)*a1;
        ab[i][1] += bflo(p.y)*a0; ac[i][1] += bfhi(p.y)*a1;
        ab[i][2] += bflo(p.z)*a0; ac[i][2] += bfhi(p.z)*a1;
        ab[i][3] += bflo(p.w)*a0; ac[i][3] += bfhi(p.w)*a1;
      }
    }
  }
#pragma unroll
  for(int i = 0; i < 2; i++){
#pragma unroll
    for(int off = 1; off <= 32; off <<= 1){ z0[i] += __shfl_xor(z0[i], off); z1[i] += __shfl_xor(z1[i], off); }
#pragma unroll
    for(int off = 16; off <= 32; off <<= 1){
      ab[i][0] += __shfl_xor(ab[i][0], off); ab[i][1] += __shfl_xor(ab[i][1], off);
      ab[i][2] += __shfl_xor(ab[i][2], off); ab[i][3] += __shfl_xor(ab[i][3], off);
      ac[i][0] += __shfl_xor(ac[i][0], off); ac[i][1] += __shfl_xor(ac[i][1], off);
      ac[i][2] += __shfl_xor(ac[i][2], off); ac[i][3] += __shfl_xor(ac[i][3], off);
    }
  }
  if(q == 0){
    int cb = 4*c4;
#pragma unroll
    for(int i = 0; i < 2; i++){
      int n = n0 + i;
      if(n >= NN) break;
      float iz0 = 1.0f/(z0[i] + 1e-16f), iz1 = 1.0f/(z1[i] + 1e-16f);
      uint2 r0, r1;
      r0.x = packbf(fmaxf(ab[i][0]*iz0 + bias[cb+0], 0.0f), fmaxf(ab[i][1]*iz0 + bias[cb+1], 0.0f));
      r0.y = packbf(fmaxf(ab[i][2]*iz0 + bias[cb+2], 0.0f), fmaxf(ab[i][3]*iz0 + bias[cb+3], 0.0f));
      r1.x = packbf(fmaxf(ac[i][0]*iz1 + bias[64+cb+0], 0.0f), fmaxf(ac[i][1]*iz1 + bias[64+cb+1], 0.0f));
      r1.y = packbf(fmaxf(ac[i][2]*iz1 + bias[64+cb+2], 0.0f), fmaxf(ac[i][3]*iz1 + bias[64+cb+3], 0.0f));
      *(uint2*)(B + (size_t)n*64 + 2*c4)      = r0;
      *(uint2*)(B + (size_t)n*64 + 32 + 2*c4) = r1;
    }
  }
}

// GAT2 (heads=2, C=32, mean) + bias + log_softmax: 2 nodes per wave; 8 lanes/edge.
__global__ void k_gat2_final(const int* __restrict__ rowptr, const int* __restrict__ rowend,
                             const unsigned short* __restrict__ srcidx16, const float* __restrict__ sS,
                             const float* __restrict__ sD, const unsigned* __restrict__ Ab,
                             const float* __restrict__ bias, void* __restrict__ out,
                             const int* __restrict__ flag, const unsigned* __restrict__ ska){
  int wid = threadIdx.x >> 6, lane = threadIdx.x & 63;
  int n0 = (blockIdx.x*4 + wid)*2;
  if(n0 >= NN) return;
  float g0, g1;
  ska_max2(ska, lane, g0, g1);
  int o = lane >> 3, c4 = lane & 7;
  int s0[2], ne[2], src[2];
  float d0[2], d1[2], m0[2], m1[2], w0[2], w1[2];
  float z0[2] = {0.f,0.f}, z1[2] = {0.f,0.f};
  float ab[2][4], ac[2][4];
#pragma unroll
  for(int i = 0; i < 2; i++){
    int n = min(n0 + i, NN-1);
    s0[i] = rowptr[n]; ne[i] = rowend[n] - s0[i];
    if(n0 + i >= NN) ne[i] = 0;
    d0[i] = sD[n*2]; d1[i] = sD[n*2+1];
    float t0 = g0 + d0[i];  m0[i] = t0 > 0.0f ? t0 : 0.2f*t0;
    float t1 = g1 + d1[i];  m1[i] = t1 > 0.0f ? t1 : 0.2f*t1;
#pragma unroll
    for(int c = 0; c < 4; c++){ ab[i][c] = 0.f; ac[i][c] = 0.f; }
  }
#pragma unroll
  for(int i = 0; i < 2; i++){
    src[i] = 0; w0[i] = 0.f; w1[i] = 0.f;
    if(lane < ne[i]){
      src[i] = (int)srcidx16[s0[i] + lane];
      float2 sv = *(const float2*)(sS + src[i]*2);
      float e0 = sv.x + d0[i]; e0 = e0 > 0.0f ? e0 : 0.2f*e0;
      float e1 = sv.y + d1[i]; e1 = e1 > 0.0f ? e1 : 0.2f*e1;
      w0[i] = __expf(e0 - m0[i]); w1[i] = __expf(e1 - m1[i]);
      z0[i] += w0[i]; z1[i] += w1[i];
    }
  }
#pragma unroll
  for(int i = 0; i < 2; i++){
#pragma unroll
    for(int j = 0; j < 8; j++){
      if(8*j >= ne[i]) break;
      int idx = 8*j + o;
      int sb = __shfl(src[i], idx);
      float a0 = __shfl(w0[i], idx), a1 = __shfl(w1[i], idx);
      uint4 p = *(const uint4*)(Ab + (size_t)sb*32 + c4*4);
      ab[i][0] += bflo(p.x)*a0; ac[i][0] += bfhi(p.x)*a1;
      ab[i][1] += bflo(p.y)*a0; ac[i][1] += bfhi(p.y)*a1;
      ab[i][2] += bflo(p.z)*a0; ac[i][2] += bfhi(p.z)*a1;
      ab[i][3] += bflo(p.w)*a0; ac[i][3] += bfhi(p.w)*a1;
    }
  }
  // rare long rows
#pragma unroll
  for(int i = 0; i < 2; i++){
    for(int base = 64; base < ne[i]; base += 64){
      int my = base + lane;
      int s = 0; float u0 = 0.f, u1 = 0.f;
      if(my < ne[i]){
        s = (int)srcidx16[s0[i] + my];
        float2 sv = *(const float2*)(sS + s*2);
        float e0 = sv.x + d0[i]; e0 = e0 > 0.0f ? e0 : 0.2f*e0;
        float e1 = sv.y + d1[i]; e1 = e1 > 0.0f ? e1 : 0.2f*e1;
        u0 = __expf(e0 - m0[i]); u1 = __expf(e1 - m1[i]);
        z0[i] += u0; z1[i] += u1;
      }
      int iters = (min(64, ne[i] - base) + 7) >> 3;
      for(int j = 0; j < iters; j++){
        int idx = 8*j + o;
        int sb = __shfl(s, idx);
        float a0 = __shfl(u0, idx), a1 = __shfl(u1, idx);
        uint4 p = *(const uint4*)(Ab + (size_t)sb*32 + c4*4);
        ab[i][0] += bflo(p.x)*a0; ac[i][0] += bfhi(p.x)*a1;
        ab[i][1] += bflo(p.y)*a0; ac[i][1] += bfhi(p.y)*a1;
        ab[i][2] += bflo(p.z)*a0; ac[i][2] += bfhi(p.z)*a1;
        ab[i][3] += bflo(p.w)*a0; ac[i][3] += bfhi(p.w)*a1;
      }
    }
  }
  int fl = *flag;
#pragma unroll
  for(int i = 0; i < 2; i++){
#pragma unroll
    for(int off = 1; off <= 32; off <<= 1){ z0[i] += __shfl_xor(z0[i], off); z1[i] += __shfl_xor(z1[i], off); }
#pragma unroll
    for(int off = 8; off <= 32; off <<= 1){
      ab[i][0] += __shfl_xor(ab[i][0], off); ab[i][1] += __shfl_xor(ab[i][1], off);
      ab[i][2] += __shfl_xor(ab[i][2], off); ab[i][3] += __shfl_xor(ab[i][3], off);
      ac[i][0] += __shfl_xor(ac[i][0], off); ac[i][1] += __shfl_xor(ac[i][1], off);
      ac[i][2] += __shfl_xor(ac[i][2], off); ac[i][3] += __shfl_xor(ac[i][3], off);
    }
    int n = n0 + i;
    if(n >= NN) continue;
    float iz0 = 1.0f/(z0[i] + 1e-16f), iz1 = 1.0f/(z1[i] + 1e-16f);
    int cb = 4*c4;
    float o0 = 0.5f*(ab[i][0]*iz0 + ac[i][0]*iz1) + bias[cb+0];
    float o1 = 0.5f*(ab[i][1]*iz0 + ac[i][1]*iz1) + bias[cb+1];
    float o2 = 0.5f*(ab[i][2]*iz0 + ac[i][2]*iz1) + bias[cb+2];
    float o3 = 0.5f*(ab[i][3]*iz0 + ac[i][3]*iz1) + bias[cb+3];
    float mx = fmaxf(fmaxf(o0, o1), fmaxf(o2, o3));
    for(int off = 4; off; off >>= 1) mx = fmaxf(mx, __shfl_xor(mx, off));
    float sm = __expf(o0 - mx) + __expf(o1 - mx) + __expf(o2 - mx) + __expf(o3 - mx);
    for(int off = 4; off; off >>= 1) sm += __shfl_xor(sm, off);
    float lse = mx + __logf(sm);
    if(o == 0){
      if(fl){
        float4 r;
        r.x = o0 - lse; r.y = o1 - lse; r.z = o2 - lse; r.w = o3 - lse;
        *(float4*)((float*)out + (size_t)n*32 + cb) = r;
      } else {
        uint2 r;
        r.x = packbf(o0 - lse, o1 - lse);
        r.y = packbf(o2 - lse, o3 - lse);
        *(uint2*)((unsigned*)out + (size_t)n*16 + 2*c4) = r;
      }
    }
  }
}

extern "C" void kernel_launch(void* const* d_in, const int* in_sizes, int n_in,
                              void* d_out, int out_size, void* d_ws, size_t ws_size,
                              hipStream_t stream) {
  const void* x   = d_in[0];
  const int*  ei  = (const int*)d_in[1];

  float* A    = (float*)d_ws;
  unsigned short* Au = (unsigned short*)A;
  unsigned* Au32 = (unsigned*)A;
  unsigned* Ab = (unsigned*)(A + (size_t)NN*64);   // +12.8MB
  float* B    = A + (size_t)NN*128;
  float* dinv = B + (size_t)NN*128;
  float* sS   = dinv + NN;
  float* sD   = sS + 2*NN;
  int* rowptr = (int*)(sD + 2*NN);
  int* rowend = rowptr + NN;
  unsigned short* srcidx16 = (unsigned short*)(rowend + NN);
  unsigned* SKA = (unsigned*)(srcidx16 + NT + 2);  // [2 gats][2 heads][32 slots]
  int* bcur   = (int*)(SKA + 128);
  unsigned* tmp = (unsigned*)(bcur + NPART*NNB*16);
  float* Wc   = (float*)(tmp + (size_t)NNB*NPART*PCAP);
  int*  flag  = (int*)(Wc + 29344);
  uintptr_t wfp = ((uintptr_t)(flag + 1) + 15) & ~(uintptr_t)15;
  unsigned short* Wf = (unsigned short*)wfp;       // 57344 ushorts (hi/lo frags)

  const float* b1c  = Wc + 8192;
  const float* b2c  = Wc + 12352;
  const float* as1c = Wc + 20608;
  const float* ad1c = Wc + 20736;
  const float* bg1c = Wc + 20864;
  const float* as2c = Wc + 29184;
  const float* ad2c = Wc + 29248;
  const float* bg2c = Wc + 29312;

  auto nb = [](long long t){ return dim3((unsigned)((t + 255)/256)); };
  dim3 g16((NN + 15)/16);       // GCN gather: 16 nodes/block (4/wave)
  dim3 g8((NN + 7)/8);          // GAT gathers: 8 nodes/block (2/wave)
  dim3 g64((NN + 63)/64);       // MFMA GEMM: 64 rows/block

  SrcPtrs sp;
  for(int i = 0; i < 12; i++) sp.p[i] = d_in[2 + i];
  k_cvtall<<<24, 256, 0, stream>>>(sp, Wc, Wf, flag, SKA);

  k_bin<<<nb(NE), 256, 0, stream>>>(ei, bcur, tmp);
  k_scatter<<<NNB, 256, 0, stream>>>(bcur, tmp, rowptr, rowend, dinv, srcidx16);

  // ---- GCN1 ----
  k_mfma<128,64,true,0,1><<<g64, 256, 0, stream>>>(
      x, Wf, Wf + 8192, dinv, Au, nullptr, nullptr, nullptr, nullptr, nullptr, flag);
  k_gcn_gather<<<g16, 256, 0, stream>>>(rowptr, rowend, srcidx16, dinv, Au32, b1c, (unsigned*)B);

  // ---- GCN2 ----
  k_mfma<64,64,true,0,0><<<g64, 256, 0, stream>>>(
      B, Wf + 16384, Wf + 20480, dinv, Au, nullptr, nullptr, nullptr, nullptr, nullptr, flag);
  k_gcn_gather<<<g16, 256, 0, stream>>>(rowptr, rowend, srcidx16, dinv, Au32, b2c, (unsigned*)B);

  // ---- GAT1: heads=2, C=64, concat ----
  k_mfma<64,128,false,64,0><<<g64, 256, 0, stream>>>(
      B, Wf + 24576, Wf + 32768, dinv, Ab, as1c, ad1c, sS, sD, SKA, flag);
  k_gat1_gather<<<g8, 256, 0, stream>>>(rowptr, rowend, srcidx16, sS, sD, Ab, bg1c, (unsigned*)B, SKA);

  // ---- GAT2: heads=2, C=32, mean + log_softmax ----
  k_mfma<128,64,false,32,0><<<g64, 256, 0, stream>>>(
      B, Wf + 40960, Wf + 49152, dinv, Ab, as2c, ad2c, sS, sD, SKA + 64, flag);
  k_gat2_final<<<g8, 256, 0, stream>>>(rowptr, rowend, srcidx16, sS, sD, Ab, bg2c, d_out, flag, SKA + 64);
}

// Round 6
// 344.421 us; speedup vs baseline: 1.0200x; 1.0200x over previous
//
#include <hip/hip_runtime.h>
#include <hip/hip_bf16.h>

typedef __hip_bfloat16 bf16;
typedef __attribute__((ext_vector_type(8))) short bf16x8;
typedef __attribute__((ext_vector_type(4))) float f32x4;

constexpr int NN = 50000;           // nodes
constexpr int NE = 800000;          // edges (without self loops)
constexpr int NT = NE + NN;         // edges incl self loops
constexpr int NNB  = (NN + 127)/128; // 391 fill buckets (128 dsts each)
constexpr int NPART = 8;             // XCD partitions (blockIdx & 7)
constexpr int PCAP = 512;            // slots per (bucket, partition); mean 256, 16 sigma

// flag-selected load: f32 storage vs bf16 storage
__device__ __forceinline__ float cvt(const void* p, long long i, int f32){
  return f32 ? ((const float*)p)[i] : __bfloat162float(((const bf16*)p)[i]);
}
// bf16 <-> f32 (RNE pack)
__device__ __forceinline__ unsigned short f2bf(float f){
  unsigned u = __float_as_uint(f);
  u += 0x7fffu + ((u >> 16) & 1);
  return (unsigned short)(u >> 16);
}
__device__ __forceinline__ float bflo(unsigned p){ return __uint_as_float(p << 16); }
__device__ __forceinline__ float bfhi(unsigned p){ return __uint_as_float(p & 0xffff0000u); }
__device__ __forceinline__ unsigned packbf(float a, float b){
  return (unsigned)f2bf(a) | ((unsigned)f2bf(b) << 16);
}
// monotone float<->uint key for atomicMax
__device__ __forceinline__ unsigned f2key(float f){
  unsigned u = __float_as_uint(f);
  return (u & 0x80000000u) ? ~u : (u | 0x80000000u);
}
__device__ __forceinline__ float key2f(unsigned k){
  unsigned u = (k & 0x80000000u) ? (k & 0x7fffffffu) : ~k;
  return __uint_as_float(u);
}

struct SrcPtrs { const void* p[12]; };
// Weight conversion (blocks 0-11: f32 copies; block 0 publishes flag)
// + MFMA fragmentation (blocks 12-15): W -> hi/lo bf16 in lane order
// + zero blocks (16-23): clear SKA + bcur (replaces hipMemsetAsync dispatch)
__global__ void k_cvtall(SrcPtrs sp, float* __restrict__ Wc,
                         unsigned short* __restrict__ Wf, int* __restrict__ flag,
                         unsigned* __restrict__ zero0){
  const int sz[12]  = {8192,64,4096,64,8192,128,128,128,8192,64,64,32};
  const int off[12] = {0,8192,8256,12352,12416,20608,20736,20864,20992,29184,29248,29312};
  int tid = threadIdx.x;
  int b = blockIdx.x;
  if(b >= 16){
    constexpr int ZN = 128 + NPART*NNB*16;   // SKA + bcur dwords
    for(int i = (b-16)*256 + tid; i < ZN; i += 8*256) zero0[i] = 0u;
    return;
  }
  __shared__ int bad;
  if(tid == 0) bad = 0;
  __syncthreads();
  const unsigned short* q = (const unsigned short*)sp.p[0];   // W1, >=16KB either dtype
  int local = 0;
  for(int i = tid; i < 8192; i += 256){
    int e = (q[i] >> 7) & 0xFF;
    if(e >= 0xC0) local = 1;
  }
  if(local) atomicOr(&bad, 1);
  __syncthreads();
  int f = bad;
  if(b == 0 && tid == 0) *flag = f;
  if(b < 12){
    const void* src = sp.p[b];
    float* dst = Wc + off[b];
    int n = sz[b];
    for(int i = tid; i < n; i += 256) dst[i] = cvt(src, i, f);
  } else {
    int g = b - 12;
    const int KK[4]   = {128, 64, 64, 128};
    const int NNo[4]  = {64, 64, 128, 64};
    const int srcI[4] = {0, 2, 4, 8};            // W1, W2, Wg1, Wg2 in sp.p
    const int foff[4] = {0, 16384, 24576, 40960};
    int K = KK[g], N = NNo[g], KF = K/32;
    const void* src = sp.p[srcI[g]];
    unsigned short* dh = Wf + foff[g];
    unsigned short* dl = dh + K*N;
    int tot = K*N;
    for(int idx = tid; idx < tot; idx += 256){
      int i = idx & 7, lane = (idx >> 3) & 63, fr = idx >> 9;
      int kf = fr % KF, nf = fr / KF;
      int k = kf*32 + ((lane >> 4) << 3) + i;
      int n = nf*16 + (lane & 15);
      float w = cvt(src, (long long)k*N + n, f);
      unsigned short h = f2bf(w);
      dh[idx] = h;
      dl[idx] = f2bf(w - __uint_as_float((unsigned)h << 16));
    }
  }
}

// ---------------- CSR build: XCD-partitioned bin -> bucket-local scatter ----------------
__global__ void k_bin(const int* __restrict__ ei, int* __restrict__ bcur,
                      unsigned* __restrict__ tmp){
  int e = blockIdx.x*256 + threadIdx.x;
  int p = blockIdx.x & (NPART-1);
  if(e < NE){
    int dst = ei[NE + e];
    int src = ei[e];
    int b = dst >> 7;
    int pos = atomicAdd(&bcur[(p*NNB + b)*16], 1);
    if(pos < PCAP) tmp[((size_t)(b*NPART + p) << 9) + pos] = (unsigned)src | ((unsigned)(dst & 127) << 16);
  }
}
__global__ void k_scatter(const int* __restrict__ bcur,
                          const unsigned* __restrict__ tmp, int* __restrict__ rowptr,
                          int* __restrict__ rowend, float* __restrict__ dinv,
                          unsigned short* __restrict__ srcidx16){
  __shared__ int hist[128];
  __shared__ int lcur[128];
  __shared__ int sh[2][128];
  __shared__ int red[256];
  int b = blockIdx.x;
  int dst0 = b << 7;
  int nd = min(128, NN - dst0);
  int tid = threadIdx.x;
  int partial = 0;
  for(int i = tid; i < b*NPART; i += 256){
    int b2 = i >> 3, p = i & 7;
    partial += bcur[(p*NNB + b2)*16];
  }
  red[tid] = partial;
  if(tid < 128) hist[tid] = 0;
  __syncthreads();
  for(int off = 128; off; off >>= 1){
    if(tid < off) red[tid] += red[tid + off];
    __syncthreads();
  }
  int base = red[0] + (b << 7);
  for(int p = 0; p < NPART; p++){
    int cnt = min(bcur[(p*NNB + b)*16], PCAP);
    const unsigned* tp = tmp + ((size_t)(b*NPART + p) << 9);
    for(int i = tid; i < cnt; i += 256) atomicAdd(&hist[tp[i] >> 16], 1);
  }
  __syncthreads();
  int c = (tid < 128) ? hist[tid] + 1 : 0;     // +1 self loop
  if(tid < 128) sh[0][tid] = c;
  __syncthreads();
  int cur = 0;
  for(int off = 1; off < 128; off <<= 1){
    int nxt = cur^1;
    if(tid < 128){
      int v = sh[cur][tid];
      if(tid >= off) v += sh[cur][tid-off];
      sh[nxt][tid] = v;
    }
    __syncthreads();
    cur = nxt;
  }
  if(tid < nd){
    int rp = base + sh[cur][tid] - c;
    int d = dst0 + tid;
    rowptr[d] = rp;
    srcidx16[rp] = (unsigned short)d;
    rowend[d] = rp + c;
    dinv[d] = rsqrtf((float)c);
    lcur[tid] = rp + 1;
  }
  __syncthreads();
  for(int p = 0; p < NPART; p++){
    int cnt = min(bcur[(p*NNB + b)*16], PCAP);
    const unsigned* tp = tmp + ((size_t)(b*NPART + p) << 9);
    for(int i = tid; i < cnt; i += 256){
      unsigned v = tp[i];
      int pos = atomicAdd(&lcur[v >> 16], 1);
      srcidx16[pos] = (unsigned short)(v & 0xffffu);
    }
  }
}

// ---------------- MFMA dense layers ----------------
template<int KIN, int KOUT, bool SCALE, int PACKC, int MODE>
__global__ void k_mfma(const void* __restrict__ X, const unsigned short* __restrict__ Wh,
                       const unsigned short* __restrict__ Wl,
                       const float* __restrict__ dinv, void* __restrict__ out,
                       const float* __restrict__ asrc, const float* __restrict__ adst,
                       float* __restrict__ sS, float* __restrict__ sD,
                       unsigned* __restrict__ ska, const int* __restrict__ flag){
  constexpr int KF = KIN/32;
  constexpr int NF = KOUT/16;
  constexpr int PITCH = KOUT + 1;
  __shared__ float Cl[64*PITCH];
  __shared__ unsigned skey[2];
  int tid = threadIdx.x;
  if(PACKC > 0 && tid < 2) skey[tid] = 0;
  int wv = tid >> 6, lane = tid & 63;
  int lr = lane >> 4, lc = lane & 15;
  int row0 = blockIdx.x*64;
  int arow = row0 + wv*16 + lc;
  if(arow >= NN) arow = NN - 1;                  // clamp: results discarded
  int f = (MODE == 1) ? *flag : 0;
  const char* xb = (const char*)X;
  f32x4 acc[NF];
#pragma unroll
  for(int nf = 0; nf < NF; nf++) acc[nf] = (f32x4){0.f,0.f,0.f,0.f};
#pragma unroll
  for(int kf = 0; kf < KF; kf++){
    bf16x8 a;
    if(MODE == 1 && f){
      const float* xf = (const float*)xb + (size_t)arow*KIN + kf*32 + lr*8;
      float4 u = *(const float4*)xf;
      float4 v = *(const float4*)(xf + 4);
      a[0]=(short)f2bf(u.x); a[1]=(short)f2bf(u.y); a[2]=(short)f2bf(u.z); a[3]=(short)f2bf(u.w);
      a[4]=(short)f2bf(v.x); a[5]=(short)f2bf(v.y); a[6]=(short)f2bf(v.z); a[7]=(short)f2bf(v.w);
    } else {
      a = *(const bf16x8*)(xb + (size_t)arow*(KIN*2) + kf*64 + lr*16);
    }
#pragma unroll
    for(int nf = 0; nf < NF; nf++){
      int fr = nf*KF + kf;
      bf16x8 wh = *(const bf16x8*)((const short*)Wh + (fr << 9) + (lane << 3));
      bf16x8 wl = *(const bf16x8*)((const short*)Wl + (fr << 9) + (lane << 3));
      acc[nf] = __builtin_amdgcn_mfma_f32_16x16x32_bf16(a, wh, acc[nf], 0, 0, 0);
      acc[nf] = __builtin_amdgcn_mfma_f32_16x16x32_bf16(a, wl, acc[nf], 0, 0, 0);
    }
  }
#pragma unroll
  for(int nf = 0; nf < NF; nf++)
#pragma unroll
    for(int r = 0; r < 4; r++)
      Cl[(wv*16 + lr*4 + r)*PITCH + nf*16 + lc] = acc[nf][r];
  __syncthreads();
  int row = tid >> 2, q = tid & 3;
  int grow = row0 + row;
  bool valid = grow < NN;
  const float* cr = &Cl[row*PITCH];
  if constexpr (PACKC == 0){
    float s = SCALE ? (valid ? dinv[grow] : 0.0f) : 1.0f;
    unsigned ov[8];
#pragma unroll
    for(int j = 0; j < 8; j++)
      ov[j] = packbf(cr[q*16 + 2*j]*s, cr[q*16 + 2*j + 1]*s);
    if(valid){
      unsigned* op = (unsigned*)out + (size_t)grow*(KOUT/2) + q*8;
      *(uint4*)op       = make_uint4(ov[0],ov[1],ov[2],ov[3]);
      *(uint4*)(op + 4) = make_uint4(ov[4],ov[5],ov[6],ov[7]);
    }
  } else {
    constexpr int C = PACKC;
    constexpr int CT = C/4;                     // cols per thread
    float s0=0.f, d0=0.f, s1=0.f, d1=0.f;
    unsigned ov[CT];
#pragma unroll
    for(int j = 0; j < CT; j++){
      int c = q*CT + j;
      float a = cr[c], bb = cr[C + c];
      ov[j] = packbf(a, bb);
      s0 += a*asrc[c];      d0 += a*adst[c];
      s1 += bb*asrc[C + c]; d1 += bb*adst[C + c];
    }
    if(valid){
      unsigned* op = (unsigned*)out + (size_t)grow*C + q*CT;
#pragma unroll
      for(int j4 = 0; j4 < CT/4; j4++)
        *(uint4*)(op + 4*j4) = make_uint4(ov[4*j4],ov[4*j4+1],ov[4*j4+2],ov[4*j4+3]);
    }
    s0 += __shfl_xor(s0,1); s0 += __shfl_xor(s0,2);
    d0 += __shfl_xor(d0,1); d0 += __shfl_xor(d0,2);
    s1 += __shfl_xor(s1,1); s1 += __shfl_xor(s1,2);
    d1 += __shfl_xor(d1,1); d1 += __shfl_xor(d1,2);
    if(valid && q == 0){
      *(float2*)(sS + 2*grow) = make_float2(s0, s1);
      *(float2*)(sD + 2*grow) = make_float2(d0, d1);
      atomicMax(&skey[0], f2key(s0));
      atomicMax(&skey[1], f2key(s1));
    }
    __syncthreads();
    if(tid < 2) atomicMax(&ska[tid*32 + (blockIdx.x & 31)], skey[tid]);
  }
}

// ---------------- gather aggregations ----------------
// GCN: 4 nodes per wave, INTERLEAVED inner loop (4 independent loads issued
// back-to-back per j-iter -> deep MLP). 8 lanes/edge. wt in {0,1} FMA masking:
// 1.0*v+acc == v+acc, 0-weight adds are no-ops -> bit-identical accumulation.
__global__ void k_gcn_gather(const int* __restrict__ rowptr, const int* __restrict__ rowend,
                             const unsigned short* __restrict__ srcidx16, const float* __restrict__ dinv,
                             const unsigned* __restrict__ Au32, const float* __restrict__ bias,
                             unsigned* __restrict__ B){
  int wid = threadIdx.x >> 6, lane = threadIdx.x & 63;
  int n0 = (blockIdx.x*4 + wid)*4;
  if(n0 >= NN) return;
  int o = lane >> 3, c4 = lane & 7;
  int s0[4], ne[4], src[4];
  float wt[4];
  float acc[4][8];
#pragma unroll
  for(int i = 0; i < 4; i++){
    int n = min(n0 + i, NN-1);
    s0[i] = rowptr[n]; ne[i] = rowend[n] - s0[i];
    if(n0 + i >= NN) ne[i] = 0;
#pragma unroll
    for(int c = 0; c < 8; c++) acc[i][c] = 0.f;
  }
#pragma unroll
  for(int i = 0; i < 4; i++){
    bool v = lane < ne[i];
    src[i] = v ? (int)srcidx16[s0[i] + lane] : 0;
    wt[i]  = v ? 1.0f : 0.0f;
  }
  int itm = 0;
#pragma unroll
  for(int i = 0; i < 4; i++) itm = max(itm, (min(ne[i],64) + 7) >> 3);
#pragma unroll 2
  for(int j = 0; j < itm; j++){
    int idx = 8*j + o;
    int sb[4]; float wb[4];
#pragma unroll
    for(int i = 0; i < 4; i++){ sb[i] = __shfl(src[i], idx); wb[i] = __shfl(wt[i], idx); }
    uint4 p[4];
#pragma unroll
    for(int i = 0; i < 4; i++) p[i] = *(const uint4*)(Au32 + (size_t)sb[i]*32 + c4*4);
#pragma unroll
    for(int i = 0; i < 4; i++){
      acc[i][0] += wb[i]*bflo(p[i].x); acc[i][1] += wb[i]*bfhi(p[i].x);
      acc[i][2] += wb[i]*bflo(p[i].y); acc[i][3] += wb[i]*bfhi(p[i].y);
      acc[i][4] += wb[i]*bflo(p[i].z); acc[i][5] += wb[i]*bfhi(p[i].z);
      acc[i][6] += wb[i]*bflo(p[i].w); acc[i][7] += wb[i]*bfhi(p[i].w);
    }
  }
  // rare long rows (ne > 64)
#pragma unroll
  for(int i = 0; i < 4; i++){
    for(int base = 64; base < ne[i]; base += 64){
      int my = base + lane;
      bool v = my < ne[i];
      int s = v ? (int)srcidx16[s0[i] + my] : 0;
      float w = v ? 1.0f : 0.0f;
      int iters = (min(64, ne[i] - base) + 7) >> 3;
      for(int j = 0; j < iters; j++){
        int sb = __shfl(s, 8*j + o);
        float wb = __shfl(w, 8*j + o);
        uint4 p = *(const uint4*)(Au32 + (size_t)sb*32 + c4*4);
        acc[i][0] += wb*bflo(p.x); acc[i][1] += wb*bfhi(p.x);
        acc[i][2] += wb*bflo(p.y); acc[i][3] += wb*bfhi(p.y);
        acc[i][4] += wb*bflo(p.z); acc[i][5] += wb*bfhi(p.z);
        acc[i][6] += wb*bflo(p.w); acc[i][7] += wb*bfhi(p.w);
      }
    }
  }
#pragma unroll
  for(int i = 0; i < 4; i++)
#pragma unroll
    for(int off = 8; off <= 32; off <<= 1){
      acc[i][0] += __shfl_xor(acc[i][0], off); acc[i][1] += __shfl_xor(acc[i][1], off);
      acc[i][2] += __shfl_xor(acc[i][2], off); acc[i][3] += __shfl_xor(acc[i][3], off);
      acc[i][4] += __shfl_xor(acc[i][4], off); acc[i][5] += __shfl_xor(acc[i][5], off);
      acc[i][6] += __shfl_xor(acc[i][6], off); acc[i][7] += __shfl_xor(acc[i][7], off);
    }
  if(o == 0){
    int cb = 8*c4;
#pragma unroll
    for(int i = 0; i < 4; i++){
      int n = n0 + i;
      if(n >= NN) break;
      float dn = dinv[n];
      uint4 r;
      r.x = packbf(fmaxf(acc[i][0]*dn + bias[cb+0], 0.0f), fmaxf(acc[i][1]*dn + bias[cb+1], 0.0f));
      r.y = packbf(fmaxf(acc[i][2]*dn + bias[cb+2], 0.0f), fmaxf(acc[i][3]*dn + bias[cb+3], 0.0f));
      r.z = packbf(fmaxf(acc[i][4]*dn + bias[cb+4], 0.0f), fmaxf(acc[i][5]*dn + bias[cb+5], 0.0f));
      r.w = packbf(fmaxf(acc[i][6]*dn + bias[cb+6], 0.0f), fmaxf(acc[i][7]*dn + bias[cb+7], 0.0f));
      *(uint4*)(B + (size_t)n*32 + c4*4) = r;
    }
  }
}

// per-wave reduction of the 32-slot spread max keys
__device__ __forceinline__ void ska_max2(const unsigned* __restrict__ ska, int lane,
                                         float& m0, float& m1){
  unsigned kk = ska[lane];
#pragma unroll
  for(int off = 1; off <= 16; off <<= 1) kk = max(kk, __shfl_xor(kk, off));
  m0 = key2f(__shfl(kk, 0));
  m1 = key2f(__shfl(kk, 32));
}

// GAT1 (heads=2, C=64, concat): 2 nodes per wave, INTERLEAVED; 16 lanes/edge.
__global__ void k_gat1_gather(const int* __restrict__ rowptr, const int* __restrict__ rowend,
                              const unsigned short* __restrict__ srcidx16, const float* __restrict__ sS,
                              const float* __restrict__ sD, const unsigned* __restrict__ Ab,
                              const float* __restrict__ bias, unsigned* __restrict__ B,
                              const unsigned* __restrict__ ska){
  int wid = threadIdx.x >> 6, lane = threadIdx.x & 63;
  int n0 = (blockIdx.x*4 + wid)*2;
  if(n0 >= NN) return;
  float g0, g1;
  ska_max2(ska, lane, g0, g1);
  int q = lane >> 4, c4 = lane & 15;
  int s0[2], ne[2], src[2];
  float d0[2], d1[2], m0[2], m1[2], w0[2], w1[2];
  float z0[2] = {0.f,0.f}, z1[2] = {0.f,0.f};
  float ab[2][4], ac[2][4];
#pragma unroll
  for(int i = 0; i < 2; i++){
    int n = min(n0 + i, NN-1);
    s0[i] = rowptr[n]; ne[i] = rowend[n] - s0[i];
    if(n0 + i >= NN) ne[i] = 0;
    d0[i] = sD[n*2]; d1[i] = sD[n*2+1];
    float t0 = g0 + d0[i];  m0[i] = t0 > 0.0f ? t0 : 0.2f*t0;
    float t1 = g1 + d1[i];  m1[i] = t1 > 0.0f ? t1 : 0.2f*t1;
#pragma unroll
    for(int c = 0; c < 4; c++){ ab[i][c] = 0.f; ac[i][c] = 0.f; }
  }
#pragma unroll
  for(int i = 0; i < 2; i++){
    src[i] = 0; w0[i] = 0.f; w1[i] = 0.f;
    if(lane < ne[i]){
      src[i] = (int)srcidx16[s0[i] + lane];
      float2 sv = *(const float2*)(sS + src[i]*2);
      float e0 = sv.x + d0[i]; e0 = e0 > 0.0f ? e0 : 0.2f*e0;
      float e1 = sv.y + d1[i]; e1 = e1 > 0.0f ? e1 : 0.2f*e1;
      w0[i] = __expf(e0 - m0[i]); w1[i] = __expf(e1 - m1[i]);
      z0[i] += w0[i]; z1[i] += w1[i];
    }
  }
  {
    int it0 = (min(ne[0],64) + 3) >> 2, it1 = (min(ne[1],64) + 3) >> 2;
    int itm = max(it0, it1);
#pragma unroll 4
    for(int j = 0; j < itm; j++){
      int idx = 4*j + q;
      int sb0 = __shfl(src[0], idx); float f00 = __shfl(w0[0], idx), f01 = __shfl(w1[0], idx);
      int sb1 = __shfl(src[1], idx); float f10 = __shfl(w0[1], idx), f11 = __shfl(w1[1], idx);
      uint4 pa = *(const uint4*)(Ab + (size_t)sb0*64 + c4*4);
      uint4 pb = *(const uint4*)(Ab + (size_t)sb1*64 + c4*4);
      ab[0][0] += bflo(pa.x)*f00; ac[0][0] += bfhi(pa.x)*f01;
      ab[0][1] += bflo(pa.y)*f00; ac[0][1] += bfhi(pa.y)*f01;
      ab[0][2] += bflo(pa.z)*f00; ac[0][2] += bfhi(pa.z)*f01;
      ab[0][3] += bflo(pa.w)*f00; ac[0][3] += bfhi(pa.w)*f01;
      ab[1][0] += bflo(pb.x)*f10; ac[1][0] += bfhi(pb.x)*f11;
      ab[1][1] += bflo(pb.y)*f10; ac[1][1] += bfhi(pb.y)*f11;
      ab[1][2] += bflo(pb.z)*f10; ac[1][2] += bfhi(pb.z)*f11;
      ab[1][3] += bflo(pb.w)*f10; ac[1][3] += bfhi(pb.w)*f11;
    }
  }
  // rare long rows
#pragma unroll
  for(int i = 0; i < 2; i++){
    for(int base = 64; base < ne[i]; base += 64){
      int my = base + lane;
      int s = 0; float u0 = 0.f, u1 = 0.f;
      if(my < ne[i]){
        s = (int)srcidx16[s0[i] + my];
        float2 sv = *(const float2*)(sS + s*2);
        float e0 = sv.x + d0[i]; e0 = e0 > 0.0f ? e0 : 0.2f*e0;
        float e1 = sv.y + d1[i]; e1 = e1 > 0.0f ? e1 : 0.2f*e1;
        u0 = __expf(e0 - m0[i]); u1 = __expf(e1 - m1[i]);
        z0[i] += u0; z1[i] += u1;
      }
      int iters = (min(64, ne[i] - base) + 3) >> 2;
      for(int j = 0; j < iters; j++){
        int idx = 4*j + q;
        int sb = __shfl(s, idx);
        float a0 = __shfl(u0, idx), a1 = __shfl(u1, idx);
        uint4 p = *(const uint4*)(Ab + (size_t)sb*64 + c4*4);
        ab[i][0] += bflo(p.x)*a0; ac[i][0] += bfhi(p.x)*a1;
        ab[i][1] += bflo(p.y)*a0; ac[i][1] += bfhi(p.y)*a1;
        ab[i][2] += bflo(p.z)*a0; ac[i][2] += bfhi(p.z)*a1;
        ab[i][3] += bflo(p.w)*a0; ac[i][3] += bfhi(p.w)*a1;
      }
    }
  }
#pragma unroll
  for(int i = 0; i < 2; i++){
#pragma unroll
    for(int off = 1; off <= 32; off <<= 1){ z0[i] += __shfl_xor(z0[i], off); z1[i] += __shfl_xor(z1[i], off); }
#pragma unroll
    for(int off = 16; off <= 32; off <<= 1){
      ab[i][0] += __shfl_xor(ab[i][0], off); ab[i][1] += __shfl_xor(ab[i][1], off);
      ab[i][2] += __shfl_xor(ab[i][2], off); ab[i][3] += __shfl_xor(ab[i][3], off);
      ac[i][0] += __shfl_xor(ac[i][0], off); ac[i][1] += __shfl_xor(ac[i][1], off);
      ac[i][2] += __shfl_xor(ac[i][2], off); ac[i][3] += __shfl_xor(ac[i][3], off);
    }
  }
  if(q == 0){
    int cb = 4*c4;
#pragma unroll
    for(int i = 0; i < 2; i++){
      int n = n0 + i;
      if(n >= NN) break;
      float iz0 = 1.0f/(z0[i] + 1e-16f), iz1 = 1.0f/(z1[i] + 1e-16f);
      uint2 r0, r1;
      r0.x = packbf(fmaxf(ab[i][0]*iz0 + bias[cb+0], 0.0f), fmaxf(ab[i][1]*iz0 + bias[cb+1], 0.0f));
      r0.y = packbf(fmaxf(ab[i][2]*iz0 + bias[cb+2], 0.0f), fmaxf(ab[i][3]*iz0 + bias[cb+3], 0.0f));
      r1.x = packbf(fmaxf(ac[i][0]*iz1 + bias[64+cb+0], 0.0f), fmaxf(ac[i][1]*iz1 + bias[64+cb+1], 0.0f));
      r1.y = packbf(fmaxf(ac[i][2]*iz1 + bias[64+cb+2], 0.0f), fmaxf(ac[i][3]*iz1 + bias[64+cb+3], 0.0f));
      *(uint2*)(B + (size_t)n*64 + 2*c4)      = r0;
      *(uint2*)(B + (size_t)n*64 + 32 + 2*c4) = r1;
    }
  }
}

// GAT2 (heads=2, C=32, mean) + bias + log_softmax: 2 nodes per wave, INTERLEAVED;
// 8 lanes/edge.
__global__ void k_gat2_final(const int* __restrict__ rowptr, const int* __restrict__ rowend,
                             const unsigned short* __restrict__ srcidx16, const float* __restrict__ sS,
                             const float* __restrict__ sD, const unsigned* __restrict__ Ab,
                             const float* __restrict__ bias, void* __restrict__ out,
                             const int* __restrict__ flag, const unsigned* __restrict__ ska){
  int wid = threadIdx.x >> 6, lane = threadIdx.x & 63;
  int n0 = (blockIdx.x*4 + wid)*2;
  if(n0 >= NN) return;
  float g0, g1;
  ska_max2(ska, lane, g0, g1);
  int o = lane >> 3, c4 = lane & 7;
  int s0[2], ne[2], src[2];
  float d0[2], d1[2], m0[2], m1[2], w0[2], w1[2];
  float z0[2] = {0.f,0.f}, z1[2] = {0.f,0.f};
  float ab[2][4], ac[2][4];
#pragma unroll
  for(int i = 0; i < 2; i++){
    int n = min(n0 + i, NN-1);
    s0[i] = rowptr[n]; ne[i] = rowend[n] - s0[i];
    if(n0 + i >= NN) ne[i] = 0;
    d0[i] = sD[n*2]; d1[i] = sD[n*2+1];
    float t0 = g0 + d0[i];  m0[i] = t0 > 0.0f ? t0 : 0.2f*t0;
    float t1 = g1 + d1[i];  m1[i] = t1 > 0.0f ? t1 : 0.2f*t1;
#pragma unroll
    for(int c = 0; c < 4; c++){ ab[i][c] = 0.f; ac[i][c] = 0.f; }
  }
#pragma unroll
  for(int i = 0; i < 2; i++){
    src[i] = 0; w0[i] = 0.f; w1[i] = 0.f;
    if(lane < ne[i]){
      src[i] = (int)srcidx16[s0[i] + lane];
      float2 sv = *(const float2*)(sS + src[i]*2);
      float e0 = sv.x + d0[i]; e0 = e0 > 0.0f ? e0 : 0.2f*e0;
      float e1 = sv.y + d1[i]; e1 = e1 > 0.0f ? e1 : 0.2f*e1;
      w0[i] = __expf(e0 - m0[i]); w1[i] = __expf(e1 - m1[i]);
      z0[i] += w0[i]; z1[i] += w1[i];
    }
  }
  {
    int it0 = (min(ne[0],64) + 7) >> 3, it1 = (min(ne[1],64) + 7) >> 3;
    int itm = max(it0, it1);
#pragma unroll 4
    for(int j = 0; j < itm; j++){
      int idx = 8*j + o;
      int sb0 = __shfl(src[0], idx); float f00 = __shfl(w0[0], idx), f01 = __shfl(w1[0], idx);
      int sb1 = __shfl(src[1], idx); float f10 = __shfl(w0[1], idx), f11 = __shfl(w1[1], idx);
      uint4 pa = *(const uint4*)(Ab + (size_t)sb0*32 + c4*4);
      uint4 pb = *(const uint4*)(Ab + (size_t)sb1*32 + c4*4);
      ab[0][0] += bflo(pa.x)*f00; ac[0][0] += bfhi(pa.x)*f01;
      ab[0][1] += bflo(pa.y)*f00; ac[0][1] += bfhi(pa.y)*f01;
      ab[0][2] += bflo(pa.z)*f00; ac[0][2] += bfhi(pa.z)*f01;
      ab[0][3] += bflo(pa.w)*f00; ac[0][3] += bfhi(pa.w)*f01;
      ab[1][0] += bflo(pb.x)*f10; ac[1][0] += bfhi(pb.x)*f11;
      ab[1][1] += bflo(pb.y)*f10; ac[1][1] += bfhi(pb.y)*f11;
      ab[1][2] += bflo(pb.z)*f10; ac[1][2] += bfhi(pb.z)*f11;
      ab[1][3] += bflo(pb.w)*f10; ac[1][3] += bfhi(pb.w)*f11;
    }
  }
  // rare long rows
#pragma unroll
  for(int i = 0; i < 2; i++){
    for(int base = 64; base < ne[i]; base += 64){
      int my = base + lane;
      int s = 0; float u0 = 0.f, u1 = 0.f;
      if(my < ne[i]){
        s = (int)srcidx16[s0[i] + my];
        float2 sv = *(const float2*)(sS + s*2);
        float e0 = sv.x + d0[i]; e0 = e0 > 0.0f ? e0 : 0.2f*e0;
        float e1 = sv.y + d1[i]; e1 = e1 > 0.0f ? e1 : 0.2f*e1;
        u0 = __expf(e0 - m0[i]); u1 = __expf(e1 - m1[i]);
        z0[i] += u0; z1[i] += u1;
      }
      int iters = (min(64, ne[i] - base) + 7) >> 3;
      for(int j = 0; j < iters; j++){
        int idx = 8*j + o;
        int sb = __shfl(s, idx);
        float a0 = __shfl(u0, idx), a1 = __shfl(u1, idx);
        uint4 p = *(const uint4*)(Ab + (size_t)sb*32 + c4*4);
        ab[i][0] += bflo(p.x)*a0; ac[i][0] += bfhi(p.x)*a1;
        ab[i][1] += bflo(p.y)*a0; ac[i][1] += bfhi(p.y)*a1;
        ab[i][2] += bflo(p.z)*a0; ac[i][2] += bfhi(p.z)*a1;
        ab[i][3] += bflo(p.w)*a0; ac[i][3] += bfhi(p.w)*a1;
      }
    }
  }
  int fl = *flag;
#pragma unroll
  for(int i = 0; i < 2; i++){
#pragma unroll
    for(int off = 1; off <= 32; off <<= 1){ z0[i] += __shfl_xor(z0[i], off); z1[i] += __shfl_xor(z1[i], off); }
#pragma unroll
    for(int off = 8; off <= 32; off <<= 1){
      ab[i][0] += __shfl_xor(ab[i][0], off); ab[i][1] += __shfl_xor(ab[i][1], off);
      ab[i][2] += __shfl_xor(ab[i][2], off); ab[i][3] += __shfl_xor(ab[i][3], off);
      ac[i][0] += __shfl_xor(ac[i][0], off); ac[i][1] += __shfl_xor(ac[i][1], off);
      ac[i][2] += __shfl_xor(ac[i][2], off); ac[i][3] += __shfl_xor(ac[i][3], off);
    }
    int n = n0 + i;
    if(n >= NN) continue;
    float iz0 = 1.0f/(z0[i] + 1e-16f), iz1 = 1.0f/(z1[i] + 1e-16f);
    int cb = 4*c4;
    float o0 = 0.5f*(ab[i][0]*iz0 + ac[i][0]*iz1) + bias[cb+0];
    float o1 = 0.5f*(ab[i][1]*iz0 + ac[i][1]*iz1) + bias[cb+1];
    float o2 = 0.5f*(ab[i][2]*iz0 + ac[i][2]*iz1) + bias[cb+2];
    float o3 = 0.5f*(ab[i][3]*iz0 + ac[i][3]*iz1) + bias[cb+3];
    float mx = fmaxf(fmaxf(o0, o1), fmaxf(o2, o3));
    for(int off = 4; off; off >>= 1) mx = fmaxf(mx, __shfl_xor(mx, off));
    float sm = __expf(o0 - mx) + __expf(o1 - mx) + __expf(o2 - mx) + __expf(o3 - mx);
    for(int off = 4; off; off >>= 1) sm += __shfl_xor(sm, off);
    float lse = mx + __logf(sm);
    if(o == 0){
      if(fl){
        float4 r;
        r.x = o0 - lse; r.y = o1 - lse; r.z = o2 - lse; r.w = o3 - lse;
        *(float4*)((float*)out + (size_t)n*32 + cb) = r;
      } else {
        uint2 r;
        r.x = packbf(o0 - lse, o1 - lse);
        r.y = packbf(o2 - lse, o3 - lse);
        *(uint2*)((unsigned*)out + (size_t)n*16 + 2*c4) = r;
      }
    }
  }
}

extern "C" void kernel_launch(void* const* d_in, const int* in_sizes, int n_in,
                              void* d_out, int out_size, void* d_ws, size_t ws_size,
                              hipStream_t stream) {
  const void* x   = d_in[0];
  const int*  ei  = (const int*)d_in[1];

  float* A    = (float*)d_ws;
  unsigned short* Au = (unsigned short*)A;
  unsigned* Au32 = (unsigned*)A;
  unsigned* Ab = (unsigned*)(A + (size_t)NN*64);   // +12.8MB
  float* B    = A + (size_t)NN*128;
  float* dinv = B + (size_t)NN*128;
  float* sS   = dinv + NN;
  float* sD   = sS + 2*NN;
  int* rowptr = (int*)(sD + 2*NN);
  int* rowend = rowptr + NN;
  unsigned short* srcidx16 = (unsigned short*)(rowend + NN);
  unsigned* SKA = (unsigned*)(srcidx16 + NT + 2);  // [2 gats][2 heads][32 slots]
  int* bcur   = (int*)(SKA + 128);
  unsigned* tmp = (unsigned*)(bcur + NPART*NNB*16);
  float* Wc   = (float*)(tmp + (size_t)NNB*NPART*PCAP);
  int*  flag  = (int*)(Wc + 29344);
  uintptr_t wfp = ((uintptr_t)(flag + 1) + 15) & ~(uintptr_t)15;
  unsigned short* Wf = (unsigned short*)wfp;       // 57344 ushorts (hi/lo frags)

  const float* b1c  = Wc + 8192;
  const float* b2c  = Wc + 12352;
  const float* as1c = Wc + 20608;
  const float* ad1c = Wc + 20736;
  const float* bg1c = Wc + 20864;
  const float* as2c = Wc + 29184;
  const float* ad2c = Wc + 29248;
  const float* bg2c = Wc + 29312;

  auto nb = [](long long t){ return dim3((unsigned)((t + 255)/256)); };
  dim3 g16((NN + 15)/16);       // GCN gather: 16 nodes/block (4/wave)
  dim3 g8((NN + 7)/8);          // GAT gathers: 8 nodes/block (2/wave)
  dim3 g64((NN + 63)/64);       // MFMA GEMM: 64 rows/block

  SrcPtrs sp;
  for(int i = 0; i < 12; i++) sp.p[i] = d_in[2 + i];
  k_cvtall<<<24, 256, 0, stream>>>(sp, Wc, Wf, flag, SKA);

  k_bin<<<nb(NE), 256, 0, stream>>>(ei, bcur, tmp);
  k_scatter<<<NNB, 256, 0, stream>>>(bcur, tmp, rowptr, rowend, dinv, srcidx16);

  // ---- GCN1 ----
  k_mfma<128,64,true,0,1><<<g64, 256, 0, stream>>>(
      x, Wf, Wf + 8192, dinv, Au, nullptr, nullptr, nullptr, nullptr, nullptr, flag);
  k_gcn_gather<<<g16, 256, 0, stream>>>(rowptr, rowend, srcidx16, dinv, Au32, b1c, (unsigned*)B);

  // ---- GCN2 ----
  k_mfma<64,64,true,0,0><<<g64, 256, 0, stream>>>(
      B, Wf + 16384, Wf + 20480, dinv, Au, nullptr, nullptr, nullptr, nullptr, nullptr, flag);
  k_gcn_gather<<<g16, 256, 0, stream>>>(rowptr, rowend, srcidx16, dinv, Au32, b2c, (unsigned*)B);

  // ---- GAT1: heads=2, C=64, concat ----
  k_mfma<64,128,false,64,0><<<g64, 256, 0, stream>>>(
      B, Wf + 24576, Wf + 32768, dinv, Ab, as1c, ad1c, sS, sD, SKA, flag);
  k_gat1_gather<<<g8, 256, 0, stream>>>(rowptr, rowend, srcidx16, sS, sD, Ab, bg1c, (unsigned*)B, SKA);

  // ---- GAT2: heads=2, C=32, mean + log_softmax ----
  k_mfma<128,64,false,32,0><<<g64, 256, 0, stream>>>(
      B, Wf + 40960, Wf + 49152, dinv, Ab, as2c, ad2c, sS, sD, SKA + 64, flag);
  k_gat2_final<<<g8, 256, 0, stream>>>(rowptr, rowend, srcidx16, sS, sD, Ab, bg2c, d_out, flag, SKA + 64);
}

// Round 7
// 343.594 us; speedup vs baseline: 1.0224x; 1.0024x over previous
//
#include <hip/hip_runtime.h>
#include <hip/hip_bf16.h>

typedef __hip_bfloat16 bf16;
typedef __attribute__((ext_vector_type(8))) short bf16x8;
typedef __attribute__((ext_vector_type(4))) float f32x4;

constexpr int NN = 50000;           // nodes
constexpr int NE = 800000;          // edges (without self loops)
constexpr int NT = NE + NN;         // edges incl self loops
constexpr int NNB  = (NN + 127)/128; // 391 fill buckets (128 dsts each)
constexpr int NPART = 8;             // XCD partitions (blockIdx & 7)
constexpr int PCAP = 512;            // slots per (bucket, partition); mean 256, 16 sigma

// flag-selected load: f32 storage vs bf16 storage
__device__ __forceinline__ float cvt(const void* p, long long i, int f32){
  return f32 ? ((const float*)p)[i] : __bfloat162float(((const bf16*)p)[i]);
}
// bf16 <-> f32 (RNE pack)
__device__ __forceinline__ unsigned short f2bf(float f){
  unsigned u = __float_as_uint(f);
  u += 0x7fffu + ((u >> 16) & 1);
  return (unsigned short)(u >> 16);
}
__device__ __forceinline__ float bflo(unsigned p){ return __uint_as_float(p << 16); }
__device__ __forceinline__ float bfhi(unsigned p){ return __uint_as_float(p & 0xffff0000u); }
__device__ __forceinline__ unsigned packbf(float a, float b){
  return (unsigned)f2bf(a) | ((unsigned)f2bf(b) << 16);
}
// monotone float<->uint key for atomicMax
__device__ __forceinline__ unsigned f2key(float f){
  unsigned u = __float_as_uint(f);
  return (u & 0x80000000u) ? ~u : (u | 0x80000000u);
}
__device__ __forceinline__ float key2f(unsigned k){
  unsigned u = (k & 0x80000000u) ? (k & 0x7fffffffu) : ~k;
  return __uint_as_float(u);
}

struct SrcPtrs { const void* p[12]; };
// Weight conversion (blocks 0-11: f32 copies; block 0 publishes flag)
// + MFMA fragmentation (blocks 12-15): W -> hi/lo bf16 in lane order
// + zero blocks (16-23): clear SKA + bcur (replaces hipMemsetAsync dispatch)
__global__ void k_cvtall(SrcPtrs sp, float* __restrict__ Wc,
                         unsigned short* __restrict__ Wf, int* __restrict__ flag,
                         unsigned* __restrict__ zero0){
  const int sz[12]  = {8192,64,4096,64,8192,128,128,128,8192,64,64,32};
  const int off[12] = {0,8192,8256,12352,12416,20608,20736,20864,20992,29184,29248,29312};
  int tid = threadIdx.x;
  int b = blockIdx.x;
  if(b >= 16){
    constexpr int ZN = 128 + NPART*NNB*16;   // SKA + bcur dwords
    for(int i = (b-16)*256 + tid; i < ZN; i += 8*256) zero0[i] = 0u;
    return;
  }
  __shared__ int bad;
  if(tid == 0) bad = 0;
  __syncthreads();
  const unsigned short* q = (const unsigned short*)sp.p[0];   // W1, >=16KB either dtype
  int local = 0;
  for(int i = tid; i < 8192; i += 256){
    int e = (q[i] >> 7) & 0xFF;
    if(e >= 0xC0) local = 1;
  }
  if(local) atomicOr(&bad, 1);
  __syncthreads();
  int f = bad;
  if(b == 0 && tid == 0) *flag = f;
  if(b < 12){
    const void* src = sp.p[b];
    float* dst = Wc + off[b];
    int n = sz[b];
    for(int i = tid; i < n; i += 256) dst[i] = cvt(src, i, f);
  } else {
    int g = b - 12;
    const int KK[4]   = {128, 64, 64, 128};
    const int NNo[4]  = {64, 64, 128, 64};
    const int srcI[4] = {0, 2, 4, 8};            // W1, W2, Wg1, Wg2 in sp.p
    const int foff[4] = {0, 16384, 24576, 40960};
    int K = KK[g], N = NNo[g], KF = K/32;
    const void* src = sp.p[srcI[g]];
    unsigned short* dh = Wf + foff[g];
    unsigned short* dl = dh + K*N;
    int tot = K*N;
    for(int idx = tid; idx < tot; idx += 256){
      int i = idx & 7, lane = (idx >> 3) & 63, fr = idx >> 9;
      int kf = fr % KF, nf = fr / KF;
      int k = kf*32 + ((lane >> 4) << 3) + i;
      int n = nf*16 + (lane & 15);
      float w = cvt(src, (long long)k*N + n, f);
      unsigned short h = f2bf(w);
      dh[idx] = h;
      dl[idx] = f2bf(w - __uint_as_float((unsigned)h << 16));
    }
  }
}

// ---------------- CSR build: XCD-partitioned bin -> bucket-local scatter ----------------
__global__ void k_bin(const int* __restrict__ ei, int* __restrict__ bcur,
                      unsigned* __restrict__ tmp){
  int e = blockIdx.x*256 + threadIdx.x;
  int p = blockIdx.x & (NPART-1);
  if(e < NE){
    int dst = ei[NE + e];
    int src = ei[e];
    int b = dst >> 7;
    int pos = atomicAdd(&bcur[(p*NNB + b)*16], 1);
    if(pos < PCAP) tmp[((size_t)(b*NPART + p) << 9) + pos] = (unsigned)src | ((unsigned)(dst & 127) << 16);
  }
}
__global__ void k_scatter(const int* __restrict__ bcur,
                          const unsigned* __restrict__ tmp, int* __restrict__ rowptr,
                          int* __restrict__ rowend, float* __restrict__ dinv,
                          unsigned short* __restrict__ srcidx16){
  __shared__ int hist[128];
  __shared__ int lcur[128];
  __shared__ int sh[2][128];
  __shared__ int red[256];
  int b = blockIdx.x;
  int dst0 = b << 7;
  int nd = min(128, NN - dst0);
  int tid = threadIdx.x;
  int partial = 0;
  for(int i = tid; i < b*NPART; i += 256){
    int b2 = i >> 3, p = i & 7;
    partial += bcur[(p*NNB + b2)*16];
  }
  red[tid] = partial;
  if(tid < 128) hist[tid] = 0;
  __syncthreads();
  for(int off = 128; off; off >>= 1){
    if(tid < off) red[tid] += red[tid + off];
    __syncthreads();
  }
  int base = red[0] + (b << 7);
  for(int p = 0; p < NPART; p++){
    int cnt = min(bcur[(p*NNB + b)*16], PCAP);
    const unsigned* tp = tmp + ((size_t)(b*NPART + p) << 9);
    for(int i = tid; i < cnt; i += 256) atomicAdd(&hist[tp[i] >> 16], 1);
  }
  __syncthreads();
  int c = (tid < 128) ? hist[tid] + 1 : 0;     // +1 self loop
  if(tid < 128) sh[0][tid] = c;
  __syncthreads();
  int cur = 0;
  for(int off = 1; off < 128; off <<= 1){
    int nxt = cur^1;
    if(tid < 128){
      int v = sh[cur][tid];
      if(tid >= off) v += sh[cur][tid-off];
      sh[nxt][tid] = v;
    }
    __syncthreads();
    cur = nxt;
  }
  if(tid < nd){
    int rp = base + sh[cur][tid] - c;
    int d = dst0 + tid;
    rowptr[d] = rp;
    srcidx16[rp] = (unsigned short)d;
    rowend[d] = rp + c;
    dinv[d] = rsqrtf((float)c);
    lcur[tid] = rp + 1;
  }
  __syncthreads();
  for(int p = 0; p < NPART; p++){
    int cnt = min(bcur[(p*NNB + b)*16], PCAP);
    const unsigned* tp = tmp + ((size_t)(b*NPART + p) << 9);
    for(int i = tid; i < cnt; i += 256){
      unsigned v = tp[i];
      int pos = atomicAdd(&lcur[v >> 16], 1);
      srcidx16[pos] = (unsigned short)(v & 0xffffu);
    }
  }
}

// ---------------- MFMA dense layers ----------------
template<int KIN, int KOUT, bool SCALE, int PACKC, int MODE>
__global__ void k_mfma(const void* __restrict__ X, const unsigned short* __restrict__ Wh,
                       const unsigned short* __restrict__ Wl,
                       const float* __restrict__ dinv, void* __restrict__ out,
                       const float* __restrict__ asrc, const float* __restrict__ adst,
                       float* __restrict__ sS, float* __restrict__ sD,
                       unsigned* __restrict__ ska, const int* __restrict__ flag){
  constexpr int KF = KIN/32;
  constexpr int NF = KOUT/16;
  constexpr int PITCH = KOUT + 1;
  __shared__ float Cl[64*PITCH];
  __shared__ unsigned skey[2];
  int tid = threadIdx.x;
  if(PACKC > 0 && tid < 2) skey[tid] = 0;
  int wv = tid >> 6, lane = tid & 63;
  int lr = lane >> 4, lc = lane & 15;
  int row0 = blockIdx.x*64;
  int arow = row0 + wv*16 + lc;
  if(arow >= NN) arow = NN - 1;                  // clamp: results discarded
  int f = (MODE == 1) ? *flag : 0;
  const char* xb = (const char*)X;
  f32x4 acc[NF];
#pragma unroll
  for(int nf = 0; nf < NF; nf++) acc[nf] = (f32x4){0.f,0.f,0.f,0.f};
#pragma unroll
  for(int kf = 0; kf < KF; kf++){
    bf16x8 a;
    if(MODE == 1 && f){
      const float* xf = (const float*)xb + (size_t)arow*KIN + kf*32 + lr*8;
      float4 u = *(const float4*)xf;
      float4 v = *(const float4*)(xf + 4);
      a[0]=(short)f2bf(u.x); a[1]=(short)f2bf(u.y); a[2]=(short)f2bf(u.z); a[3]=(short)f2bf(u.w);
      a[4]=(short)f2bf(v.x); a[5]=(short)f2bf(v.y); a[6]=(short)f2bf(v.z); a[7]=(short)f2bf(v.w);
    } else {
      a = *(const bf16x8*)(xb + (size_t)arow*(KIN*2) + kf*64 + lr*16);
    }
#pragma unroll
    for(int nf = 0; nf < NF; nf++){
      int fr = nf*KF + kf;
      bf16x8 wh = *(const bf16x8*)((const short*)Wh + (fr << 9) + (lane << 3));
      bf16x8 wl = *(const bf16x8*)((const short*)Wl + (fr << 9) + (lane << 3));
      acc[nf] = __builtin_amdgcn_mfma_f32_16x16x32_bf16(a, wh, acc[nf], 0, 0, 0);
      acc[nf] = __builtin_amdgcn_mfma_f32_16x16x32_bf16(a, wl, acc[nf], 0, 0, 0);
    }
  }
#pragma unroll
  for(int nf = 0; nf < NF; nf++)
#pragma unroll
    for(int r = 0; r < 4; r++)
      Cl[(wv*16 + lr*4 + r)*PITCH + nf*16 + lc] = acc[nf][r];
  __syncthreads();
  int row = tid >> 2, q = tid & 3;
  int grow = row0 + row;
  bool valid = grow < NN;
  const float* cr = &Cl[row*PITCH];
  if constexpr (PACKC == 0){
    float s = SCALE ? (valid ? dinv[grow] : 0.0f) : 1.0f;
    unsigned ov[8];
#pragma unroll
    for(int j = 0; j < 8; j++)
      ov[j] = packbf(cr[q*16 + 2*j]*s, cr[q*16 + 2*j + 1]*s);
    if(valid){
      unsigned* op = (unsigned*)out + (size_t)grow*(KOUT/2) + q*8;
      *(uint4*)op       = make_uint4(ov[0],ov[1],ov[2],ov[3]);
      *(uint4*)(op + 4) = make_uint4(ov[4],ov[5],ov[6],ov[7]);
    }
  } else {
    constexpr int C = PACKC;
    constexpr int CT = C/4;                     // cols per thread
    float s0=0.f, d0=0.f, s1=0.f, d1=0.f;
    unsigned ov[CT];
#pragma unroll
    for(int j = 0; j < CT; j++){
      int c = q*CT + j;
      float a = cr[c], bb = cr[C + c];
      ov[j] = packbf(a, bb);
      s0 += a*asrc[c];      d0 += a*adst[c];
      s1 += bb*asrc[C + c]; d1 += bb*adst[C + c];
    }
    if(valid){
      unsigned* op = (unsigned*)out + (size_t)grow*C + q*CT;
#pragma unroll
      for(int j4 = 0; j4 < CT/4; j4++)
        *(uint4*)(op + 4*j4) = make_uint4(ov[4*j4],ov[4*j4+1],ov[4*j4+2],ov[4*j4+3]);
    }
    s0 += __shfl_xor(s0,1); s0 += __shfl_xor(s0,2);
    d0 += __shfl_xor(d0,1); d0 += __shfl_xor(d0,2);
    s1 += __shfl_xor(s1,1); s1 += __shfl_xor(s1,2);
    d1 += __shfl_xor(d1,1); d1 += __shfl_xor(d1,2);
    if(valid && q == 0){
      *(float2*)(sS + 2*grow) = make_float2(s0, s1);
      *(float2*)(sD + 2*grow) = make_float2(d0, d1);
      atomicMax(&skey[0], f2key(s0));
      atomicMax(&skey[1], f2key(s1));
    }
    __syncthreads();
    if(tid < 2) atomicMax(&ska[tid*32 + (blockIdx.x & 31)], skey[tid]);
  }
}

// ---------------- gather aggregations ----------------
// Shuffle-free gathers: prologue stages per-edge metadata (src [,w0,w1]) into a
// wave-local LDS scratchpad (all 64 slots initialized; padded slots w=0/src=0).
// The j-loop reads meta via ds_read (no cross-lane register deps) -> compiler can
// cluster row loads across unrolled iterations for deep MLP.
// Per-lane accumulation sequence identical to prior version -> bit-identical.

// GCN: 4 nodes per wave; 8 lanes/edge; one load instr covers 8 rows (1KB).
__global__ void k_gcn_gather(const int* __restrict__ rowptr, const int* __restrict__ rowend,
                             const unsigned short* __restrict__ srcidx16, const float* __restrict__ dinv,
                             const unsigned* __restrict__ Au32, const float* __restrict__ bias,
                             unsigned* __restrict__ B){
  __shared__ unsigned short lsrc[4][4*64];
  int wid = threadIdx.x >> 6, lane = threadIdx.x & 63;
  int n0 = (blockIdx.x*4 + wid)*4;
  if(n0 >= NN) return;
  int o = lane >> 3, c4 = lane & 7;
  unsigned short* ls = lsrc[wid];
  int s0[4], ne[4];
  float acc[4][8];
#pragma unroll
  for(int i = 0; i < 4; i++){
    int n = min(n0 + i, NN-1);
    s0[i] = rowptr[n]; ne[i] = rowend[n] - s0[i];
    if(n0 + i >= NN) ne[i] = 0;
#pragma unroll
    for(int c = 0; c < 8; c++) acc[i][c] = 0.f;
  }
#pragma unroll
  for(int i = 0; i < 4; i++){
    int e = min(lane, max(ne[i]-1, 0));
    unsigned short sv = srcidx16[s0[i] + e];
    ls[i*64 + lane] = (lane < ne[i]) ? sv : (unsigned short)0;
  }
  int itm = 0;
#pragma unroll
  for(int i = 0; i < 4; i++) itm = max(itm, (min(ne[i],64) + 7) >> 3);
#pragma unroll 2
  for(int j = 0; j < itm; j++){
    int idx = 8*j + o;                      // <= 63
    int sb[4]; float w[4]; uint4 p[4];
#pragma unroll
    for(int i = 0; i < 4; i++){
      sb[i] = (int)ls[i*64 + idx];
      w[i] = (idx < ne[i]) ? 1.0f : 0.0f;
    }
#pragma unroll
    for(int i = 0; i < 4; i++) p[i] = *(const uint4*)(Au32 + (size_t)sb[i]*32 + c4*4);
#pragma unroll
    for(int i = 0; i < 4; i++){
      acc[i][0] += w[i]*bflo(p[i].x); acc[i][1] += w[i]*bfhi(p[i].x);
      acc[i][2] += w[i]*bflo(p[i].y); acc[i][3] += w[i]*bfhi(p[i].y);
      acc[i][4] += w[i]*bflo(p[i].z); acc[i][5] += w[i]*bfhi(p[i].z);
      acc[i][6] += w[i]*bflo(p[i].w); acc[i][7] += w[i]*bfhi(p[i].w);
    }
  }
  // rare long rows (ne > 64): global path, shuffle-based (cold)
#pragma unroll
  for(int i = 0; i < 4; i++){
    for(int base = 64; base < ne[i]; base += 64){
      int my = base + lane;
      bool v = my < ne[i];
      int s = v ? (int)srcidx16[s0[i] + my] : 0;
      float w = v ? 1.0f : 0.0f;
      int iters = (min(64, ne[i] - base) + 7) >> 3;
      for(int j = 0; j < iters; j++){
        int sb = __shfl(s, 8*j + o);
        float wb = __shfl(w, 8*j + o);
        uint4 p = *(const uint4*)(Au32 + (size_t)sb*32 + c4*4);
        acc[i][0] += wb*bflo(p.x); acc[i][1] += wb*bfhi(p.x);
        acc[i][2] += wb*bflo(p.y); acc[i][3] += wb*bfhi(p.y);
        acc[i][4] += wb*bflo(p.z); acc[i][5] += wb*bfhi(p.z);
        acc[i][6] += wb*bflo(p.w); acc[i][7] += wb*bfhi(p.w);
      }
    }
  }
#pragma unroll
  for(int i = 0; i < 4; i++)
#pragma unroll
    for(int off = 8; off <= 32; off <<= 1){
      acc[i][0] += __shfl_xor(acc[i][0], off); acc[i][1] += __shfl_xor(acc[i][1], off);
      acc[i][2] += __shfl_xor(acc[i][2], off); acc[i][3] += __shfl_xor(acc[i][3], off);
      acc[i][4] += __shfl_xor(acc[i][4], off); acc[i][5] += __shfl_xor(acc[i][5], off);
      acc[i][6] += __shfl_xor(acc[i][6], off); acc[i][7] += __shfl_xor(acc[i][7], off);
    }
  if(o == 0){
    int cb = 8*c4;
#pragma unroll
    for(int i = 0; i < 4; i++){
      int n = n0 + i;
      if(n >= NN) break;
      float dn = dinv[n];
      uint4 r;
      r.x = packbf(fmaxf(acc[i][0]*dn + bias[cb+0], 0.0f), fmaxf(acc[i][1]*dn + bias[cb+1], 0.0f));
      r.y = packbf(fmaxf(acc[i][2]*dn + bias[cb+2], 0.0f), fmaxf(acc[i][3]*dn + bias[cb+3], 0.0f));
      r.z = packbf(fmaxf(acc[i][4]*dn + bias[cb+4], 0.0f), fmaxf(acc[i][5]*dn + bias[cb+5], 0.0f));
      r.w = packbf(fmaxf(acc[i][6]*dn + bias[cb+6], 0.0f), fmaxf(acc[i][7]*dn + bias[cb+7], 0.0f));
      *(uint4*)(B + (size_t)n*32 + c4*4) = r;
    }
  }
}

// per-wave reduction of the 32-slot spread max keys
__device__ __forceinline__ void ska_max2(const unsigned* __restrict__ ska, int lane,
                                         float& m0, float& m1){
  unsigned kk = ska[lane];
#pragma unroll
  for(int off = 1; off <= 16; off <<= 1) kk = max(kk, __shfl_xor(kk, off));
  m0 = key2f(__shfl(kk, 0));
  m1 = key2f(__shfl(kk, 32));
}

// GAT1 (heads=2, C=64, concat): 2 nodes per wave; 16 lanes/edge; LDS meta.
__global__ void k_gat1_gather(const int* __restrict__ rowptr, const int* __restrict__ rowend,
                              const unsigned short* __restrict__ srcidx16, const float* __restrict__ sS,
                              const float* __restrict__ sD, const unsigned* __restrict__ Ab,
                              const float* __restrict__ bias, unsigned* __restrict__ B,
                              const unsigned* __restrict__ ska){
  __shared__ unsigned short lsrc[4][2*64];
  __shared__ float lw0[4][2*64];
  __shared__ float lw1[4][2*64];
  int wid = threadIdx.x >> 6, lane = threadIdx.x & 63;
  int n0 = (blockIdx.x*4 + wid)*2;
  if(n0 >= NN) return;
  float g0, g1;
  ska_max2(ska, lane, g0, g1);
  int q = lane >> 4, c4 = lane & 15;
  int s0[2], ne[2];
  float d0[2], d1[2], m0[2], m1[2];
  float z0[2] = {0.f,0.f}, z1[2] = {0.f,0.f};
  float ab[2][4], ac[2][4];
#pragma unroll
  for(int i = 0; i < 2; i++){
    int n = min(n0 + i, NN-1);
    s0[i] = rowptr[n]; ne[i] = rowend[n] - s0[i];
    if(n0 + i >= NN) ne[i] = 0;
    d0[i] = sD[n*2]; d1[i] = sD[n*2+1];
    float t0 = g0 + d0[i];  m0[i] = t0 > 0.0f ? t0 : 0.2f*t0;
    float t1 = g1 + d1[i];  m1[i] = t1 > 0.0f ? t1 : 0.2f*t1;
#pragma unroll
    for(int c = 0; c < 4; c++){ ab[i][c] = 0.f; ac[i][c] = 0.f; }
  }
#pragma unroll
  for(int i = 0; i < 2; i++){
    int e = min(lane, max(ne[i]-1, 0));
    int src = (int)srcidx16[s0[i] + e];
    bool v = lane < ne[i];
    float2 sv = *(const float2*)(sS + src*2);
    float e0 = sv.x + d0[i]; e0 = e0 > 0.0f ? e0 : 0.2f*e0;
    float e1 = sv.y + d1[i]; e1 = e1 > 0.0f ? e1 : 0.2f*e1;
    float w0v = v ? __expf(e0 - m0[i]) : 0.0f;
    float w1v = v ? __expf(e1 - m1[i]) : 0.0f;
    z0[i] += w0v; z1[i] += w1v;
    lsrc[wid][i*64 + lane] = (unsigned short)(v ? src : 0);
    lw0[wid][i*64 + lane] = w0v;
    lw1[wid][i*64 + lane] = w1v;
  }
  {
    int it0 = (min(ne[0],64) + 3) >> 2, it1 = (min(ne[1],64) + 3) >> 2;
    int itm = max(it0, it1);
#pragma unroll 4
    for(int j = 0; j < itm; j++){
      int idx = 4*j + q;                    // <= 63
      int sb0 = (int)lsrc[wid][idx];
      float f00 = lw0[wid][idx], f01 = lw1[wid][idx];
      int sb1 = (int)lsrc[wid][64 + idx];
      float f10 = lw0[wid][64 + idx], f11 = lw1[wid][64 + idx];
      uint4 pa = *(const uint4*)(Ab + (size_t)sb0*64 + c4*4);
      uint4 pb = *(const uint4*)(Ab + (size_t)sb1*64 + c4*4);
      ab[0][0] += bflo(pa.x)*f00; ac[0][0] += bfhi(pa.x)*f01;
      ab[0][1] += bflo(pa.y)*f00; ac[0][1] += bfhi(pa.y)*f01;
      ab[0][2] += bflo(pa.z)*f00; ac[0][2] += bfhi(pa.z)*f01;
      ab[0][3] += bflo(pa.w)*f00; ac[0][3] += bfhi(pa.w)*f01;
      ab[1][0] += bflo(pb.x)*f10; ac[1][0] += bfhi(pb.x)*f11;
      ab[1][1] += bflo(pb.y)*f10; ac[1][1] += bfhi(pb.y)*f11;
      ab[1][2] += bflo(pb.z)*f10; ac[1][2] += bfhi(pb.z)*f11;
      ab[1][3] += bflo(pb.w)*f10; ac[1][3] += bfhi(pb.w)*f11;
    }
  }
  // rare long rows: global shuffle path (cold)
#pragma unroll
  for(int i = 0; i < 2; i++){
    for(int base = 64; base < ne[i]; base += 64){
      int my = base + lane;
      int s = 0; float u0 = 0.f, u1 = 0.f;
      if(my < ne[i]){
        s = (int)srcidx16[s0[i] + my];
        float2 sv = *(const float2*)(sS + s*2);
        float e0 = sv.x + d0[i]; e0 = e0 > 0.0f ? e0 : 0.2f*e0;
        float e1 = sv.y + d1[i]; e1 = e1 > 0.0f ? e1 : 0.2f*e1;
        u0 = __expf(e0 - m0[i]); u1 = __expf(e1 - m1[i]);
        z0[i] += u0; z1[i] += u1;
      }
      int iters = (min(64, ne[i] - base) + 3) >> 2;
      for(int j = 0; j < iters; j++){
        int idx = 4*j + q;
        int sb = __shfl(s, idx);
        float a0 = __shfl(u0, idx), a1 = __shfl(u1, idx);
        uint4 p = *(const uint4*)(Ab + (size_t)sb*64 + c4*4);
        ab[i][0] += bflo(p.x)*a0; ac[i][0] += bfhi(p.x)*a1;
        ab[i][1] += bflo(p.y)*a0; ac[i][1] += bfhi(p.y)*a1;
        ab[i][2] += bflo(p.z)*a0; ac[i][2] += bfhi(p.z)*a1;
        ab[i][3] += bflo(p.w)*a0; ac[i][3] += bfhi(p.w)*a1;
      }
    }
  }
#pragma unroll
  for(int i = 0; i < 2; i++){
#pragma unroll
    for(int off = 1; off <= 32; off <<= 1){ z0[i] += __shfl_xor(z0[i], off); z1[i] += __shfl_xor(z1[i], off); }
#pragma unroll
    for(int off = 16; off <= 32; off <<= 1){
      ab[i][0] += __shfl_xor(ab[i][0], off); ab[i][1] += __shfl_xor(ab[i][1], off);
      ab[i][2] += __shfl_xor(ab[i][2], off); ab[i][3] += __shfl_xor(ab[i][3], off);
      ac[i][0] += __shfl_xor(ac[i][0], off); ac[i][1] += __shfl_xor(ac[i][1], off);
      ac[i][2] += __shfl_xor(ac[i][2], off); ac[i][3] += __shfl_xor(ac[i][3], off);
    }
  }
  if(q == 0){
    int cb = 4*c4;
#pragma unroll
    for(int i = 0; i < 2; i++){
      int n = n0 + i;
      if(n >= NN) break;
      float iz0 = 1.0f/(z0[i] + 1e-16f), iz1 = 1.0f/(z1[i] + 1e-16f);
      uint2 r0, r1;
      r0.x = packbf(fmaxf(ab[i][0]*iz0 + bias[cb+0], 0.0f), fmaxf(ab[i][1]*iz0 + bias[cb+1], 0.0f));
      r0.y = packbf(fmaxf(ab[i][2]*iz0 + bias[cb+2], 0.0f), fmaxf(ab[i][3]*iz0 + bias[cb+3], 0.0f));
      r1.x = packbf(fmaxf(ac[i][0]*iz1 + bias[64+cb+0], 0.0f), fmaxf(ac[i][1]*iz1 + bias[64+cb+1], 0.0f));
      r1.y = packbf(fmaxf(ac[i][2]*iz1 + bias[64+cb+2], 0.0f), fmaxf(ac[i][3]*iz1 + bias[64+cb+3], 0.0f));
      *(uint2*)(B + (size_t)n*64 + 2*c4)      = r0;
      *(uint2*)(B + (size_t)n*64 + 32 + 2*c4) = r1;
    }
  }
}

// GAT2 (heads=2, C=32, mean) + bias + log_softmax: 2 nodes per wave; 8 lanes/edge; LDS meta.
__global__ void k_gat2_final(const int* __restrict__ rowptr, const int* __restrict__ rowend,
                             const unsigned short* __restrict__ srcidx16, const float* __restrict__ sS,
                             const float* __restrict__ sD, const unsigned* __restrict__ Ab,
                             const float* __restrict__ bias, void* __restrict__ out,
                             const int* __restrict__ flag, const unsigned* __restrict__ ska){
  __shared__ unsigned short lsrc[4][2*64];
  __shared__ float lw0[4][2*64];
  __shared__ float lw1[4][2*64];
  int wid = threadIdx.x >> 6, lane = threadIdx.x & 63;
  int n0 = (blockIdx.x*4 + wid)*2;
  if(n0 >= NN) return;
  float g0, g1;
  ska_max2(ska, lane, g0, g1);
  int o = lane >> 3, c4 = lane & 7;
  int s0[2], ne[2];
  float d0[2], d1[2], m0[2], m1[2];
  float z0[2] = {0.f,0.f}, z1[2] = {0.f,0.f};
  float ab[2][4], ac[2][4];
#pragma unroll
  for(int i = 0; i < 2; i++){
    int n = min(n0 + i, NN-1);
    s0[i] = rowptr[n]; ne[i] = rowend[n] - s0[i];
    if(n0 + i >= NN) ne[i] = 0;
    d0[i] = sD[n*2]; d1[i] = sD[n*2+1];
    float t0 = g0 + d0[i];  m0[i] = t0 > 0.0f ? t0 : 0.2f*t0;
    float t1 = g1 + d1[i];  m1[i] = t1 > 0.0f ? t1 : 0.2f*t1;
#pragma unroll
    for(int c = 0; c < 4; c++){ ab[i][c] = 0.f; ac[i][c] = 0.f; }
  }
#pragma unroll
  for(int i = 0; i < 2; i++){
    int e = min(lane, max(ne[i]-1, 0));
    int src = (int)srcidx16[s0[i] + e];
    bool v = lane < ne[i];
    float2 sv = *(const float2*)(sS + src*2);
    float e0 = sv.x + d0[i]; e0 = e0 > 0.0f ? e0 : 0.2f*e0;
    float e1 = sv.y + d1[i]; e1 = e1 > 0.0f ? e1 : 0.2f*e1;
    float w0v = v ? __expf(e0 - m0[i]) : 0.0f;
    float w1v = v ? __expf(e1 - m1[i]) : 0.0f;
    z0[i] += w0v; z1[i] += w1v;
    lsrc[wid][i*64 + lane] = (unsigned short)(v ? src : 0);
    lw0[wid][i*64 + lane] = w0v;
    lw1[wid][i*64 + lane] = w1v;
  }
  {
    int it0 = (min(ne[0],64) + 7) >> 3, it1 = (min(ne[1],64) + 7) >> 3;
    int itm = max(it0, it1);
#pragma unroll 4
    for(int j = 0; j < itm; j++){
      int idx = 8*j + o;                    // <= 63
      int sb0 = (int)lsrc[wid][idx];
      float f00 = lw0[wid][idx], f01 = lw1[wid][idx];
      int sb1 = (int)lsrc[wid][64 + idx];
      float f10 = lw0[wid][64 + idx], f11 = lw1[wid][64 + idx];
      uint4 pa = *(const uint4*)(Ab + (size_t)sb0*32 + c4*4);
      uint4 pb = *(const uint4*)(Ab + (size_t)sb1*32 + c4*4);
      ab[0][0] += bflo(pa.x)*f00; ac[0][0] += bfhi(pa.x)*f01;
      ab[0][1] += bflo(pa.y)*f00; ac[0][1] += bfhi(pa.y)*f01;
      ab[0][2] += bflo(pa.z)*f00; ac[0][2] += bfhi(pa.z)*f01;
      ab[0][3] += bflo(pa.w)*f00; ac[0][3] += bfhi(pa.w)*f01;
      ab[1][0] += bflo(pb.x)*f10; ac[1][0] += bfhi(pb.x)*f11;
      ab[1][1] += bflo(pb.y)*f10; ac[1][1] += bfhi(pb.y)*f11;
      ab[1][2] += bflo(pb.z)*f10; ac[1][2] += bfhi(pb.z)*f11;
      ab[1][3] += bflo(pb.w)*f10; ac[1][3] += bfhi(pb.w)*f11;
    }
  }
  // rare long rows: global shuffle path (cold)
#pragma unroll
  for(int i = 0; i < 2; i++){
    for(int base = 64; base < ne[i]; base += 64){
      int my = base + lane;
      int s = 0; float u0 = 0.f, u1 = 0.f;
      if(my < ne[i]){
        s = (int)srcidx16[s0[i] + my];
        float2 sv = *(const float2*)(sS + s*2);
        float e0 = sv.x + d0[i]; e0 = e0 > 0.0f ? e0 : 0.2f*e0;
        float e1 = sv.y + d1[i]; e1 = e1 > 0.0f ? e1 : 0.2f*e1;
        u0 = __expf(e0 - m0[i]); u1 = __expf(e1 - m1[i]);
        z0[i] += u0; z1[i] += u1;
      }
      int iters = (min(64, ne[i] - base) + 7) >> 3;
      for(int j = 0; j < iters; j++){
        int idx = 8*j + o;
        int sb = __shfl(s, idx);
        float a0 = __shfl(u0, idx), a1 = __shfl(u1, idx);
        uint4 p = *(const uint4*)(Ab + (size_t)sb*32 + c4*4);
        ab[i][0] += bflo(p.x)*a0; ac[i][0] += bfhi(p.x)*a1;
        ab[i][1] += bflo(p.y)*a0; ac[i][1] += bfhi(p.y)*a1;
        ab[i][2] += bflo(p.z)*a0; ac[i][2] += bfhi(p.z)*a1;
        ab[i][3] += bflo(p.w)*a0; ac[i][3] += bfhi(p.w)*a1;
      }
    }
  }
  int fl = *flag;
#pragma unroll
  for(int i = 0; i < 2; i++){
#pragma unroll
    for(int off = 1; off <= 32; off <<= 1){ z0[i] += __shfl_xor(z0[i], off); z1[i] += __shfl_xor(z1[i], off); }
#pragma unroll
    for(int off = 8; off <= 32; off <<= 1){
      ab[i][0] += __shfl_xor(ab[i][0], off); ab[i][1] += __shfl_xor(ab[i][1], off);
      ab[i][2] += __shfl_xor(ab[i][2], off); ab[i][3] += __shfl_xor(ab[i][3], off);
      ac[i][0] += __shfl_xor(ac[i][0], off); ac[i][1] += __shfl_xor(ac[i][1], off);
      ac[i][2] += __shfl_xor(ac[i][2], off); ac[i][3] += __shfl_xor(ac[i][3], off);
    }
    int n = n0 + i;
    if(n >= NN) continue;
    float iz0 = 1.0f/(z0[i] + 1e-16f), iz1 = 1.0f/(z1[i] + 1e-16f);
    int cb = 4*c4;
    float o0 = 0.5f*(ab[i][0]*iz0 + ac[i][0]*iz1) + bias[cb+0];
    float o1 = 0.5f*(ab[i][1]*iz0 + ac[i][1]*iz1) + bias[cb+1];
    float o2 = 0.5f*(ab[i][2]*iz0 + ac[i][2]*iz1) + bias[cb+2];
    float o3 = 0.5f*(ab[i][3]*iz0 + ac[i][3]*iz1) + bias[cb+3];
    float mx = fmaxf(fmaxf(o0, o1), fmaxf(o2, o3));
    for(int off = 4; off; off >>= 1) mx = fmaxf(mx, __shfl_xor(mx, off));
    float sm = __expf(o0 - mx) + __expf(o1 - mx) + __expf(o2 - mx) + __expf(o3 - mx);
    for(int off = 4; off; off >>= 1) sm += __shfl_xor(sm, off);
    float lse = mx + __logf(sm);
    if(o == 0){
      if(fl){
        float4 r;
        r.x = o0 - lse; r.y = o1 - lse; r.z = o2 - lse; r.w = o3 - lse;
        *(float4*)((float*)out + (size_t)n*32 + cb) = r;
      } else {
        uint2 r;
        r.x = packbf(o0 - lse, o1 - lse);
        r.y = packbf(o2 - lse, o3 - lse);
        *(uint2*)((unsigned*)out + (size_t)n*16 + 2*c4) = r;
      }
    }
  }
}

extern "C" void kernel_launch(void* const* d_in, const int* in_sizes, int n_in,
                              void* d_out, int out_size, void* d_ws, size_t ws_size,
                              hipStream_t stream) {
  const void* x   = d_in[0];
  const int*  ei  = (const int*)d_in[1];

  float* A    = (float*)d_ws;
  unsigned short* Au = (unsigned short*)A;
  unsigned* Au32 = (unsigned*)A;
  unsigned* Ab = (unsigned*)(A + (size_t)NN*64);   // +12.8MB
  float* B    = A + (size_t)NN*128;
  float* dinv = B + (size_t)NN*128;
  float* sS   = dinv + NN;
  float* sD   = sS + 2*NN;
  int* rowptr = (int*)(sD + 2*NN);
  int* rowend = rowptr + NN;
  unsigned short* srcidx16 = (unsigned short*)(rowend + NN);
  unsigned* SKA = (unsigned*)(srcidx16 + NT + 2);  // [2 gats][2 heads][32 slots]
  int* bcur   = (int*)(SKA + 128);
  unsigned* tmp = (unsigned*)(bcur + NPART*NNB*16);
  float* Wc   = (float*)(tmp + (size_t)NNB*NPART*PCAP);
  int*  flag  = (int*)(Wc + 29344);
  uintptr_t wfp = ((uintptr_t)(flag + 1) + 15) & ~(uintptr_t)15;
  unsigned short* Wf = (unsigned short*)wfp;       // 57344 ushorts (hi/lo frags)

  const float* b1c  = Wc + 8192;
  const float* b2c  = Wc + 12352;
  const float* as1c = Wc + 20608;
  const float* ad1c = Wc + 20736;
  const float* bg1c = Wc + 20864;
  const float* as2c = Wc + 29184;
  const float* ad2c = Wc + 29248;
  const float* bg2c = Wc + 29312;

  auto nb = [](long long t){ return dim3((unsigned)((t + 255)/256)); };
  dim3 g16((NN + 15)/16);       // GCN gather: 16 nodes/block (4/wave)
  dim3 g8((NN + 7)/8);          // GAT gathers: 8 nodes/block (2/wave)
  dim3 g64((NN + 63)/64);       // MFMA GEMM: 64 rows/block

  SrcPtrs sp;
  for(int i = 0; i < 12; i++) sp.p[i] = d_in[2 + i];
  k_cvtall<<<24, 256, 0, stream>>>(sp, Wc, Wf, flag, SKA);

  k_bin<<<nb(NE), 256, 0, stream>>>(ei, bcur, tmp);
  k_scatter<<<NNB, 256, 0, stream>>>(bcur, tmp, rowptr, rowend, dinv, srcidx16);

  // ---- GCN1 ----
  k_mfma<128,64,true,0,1><<<g64, 256, 0, stream>>>(
      x, Wf, Wf + 8192, dinv, Au, nullptr, nullptr, nullptr, nullptr, nullptr, flag);
  k_gcn_gather<<<g16, 256, 0, stream>>>(rowptr, rowend, srcidx16, dinv, Au32, b1c, (unsigned*)B);

  // ---- GCN2 ----
  k_mfma<64,64,true,0,0><<<g64, 256, 0, stream>>>(
      B, Wf + 16384, Wf + 20480, dinv, Au, nullptr, nullptr, nullptr, nullptr, nullptr, flag);
  k_gcn_gather<<<g16, 256, 0, stream>>>(rowptr, rowend, srcidx16, dinv, Au32, b2c, (unsigned*)B);

  // ---- GAT1: heads=2, C=64, concat ----
  k_mfma<64,128,false,64,0><<<g64, 256, 0, stream>>>(
      B, Wf + 24576, Wf + 32768, dinv, Ab, as1c, ad1c, sS, sD, SKA, flag);
  k_gat1_gather<<<g8, 256, 0, stream>>>(rowptr, rowend, srcidx16, sS, sD, Ab, bg1c, (unsigned*)B, SKA);

  // ---- GAT2: heads=2, C=32, mean + log_softmax ----
  k_mfma<128,64,false,32,0><<<g64, 256, 0, stream>>>(
      B, Wf + 40960, Wf + 49152, dinv, Ab, as2c, ad2c, sS, sD, SKA + 64, flag);
  k_gat2_final<<<g8, 256, 0, stream>>>(rowptr, rowend, srcidx16, sS, sD, Ab, bg2c, d_out, flag, SKA + 64);
}

// Round 8
// 324.452 us; speedup vs baseline: 1.0827x; 1.0590x over previous
//
#include <hip/hip_runtime.h>
#include <hip/hip_bf16.h>

typedef __hip_bfloat16 bf16;
typedef __attribute__((ext_vector_type(8))) short bf16x8;
typedef __attribute__((ext_vector_type(4))) float f32x4;

constexpr int NN = 50000;           // nodes
constexpr int NE = 800000;          // edges (without self loops)
constexpr int NT = NE + NN;         // edges incl self loops
constexpr int NNB  = (NN + 127)/128; // 391 fill buckets (128 dsts each)
constexpr int NPART = 8;             // XCD partitions (blockIdx & 7)
constexpr int PCAP = 512;            // slots per (bucket, partition); mean 256, 16 sigma
constexpr int BINB = 1024;           // edges per k_bin block

// flag-selected load: f32 storage vs bf16 storage
__device__ __forceinline__ float cvt(const void* p, long long i, int f32){
  return f32 ? ((const float*)p)[i] : __bfloat162float(((const bf16*)p)[i]);
}
// bf16 <-> f32 (RNE pack)
__device__ __forceinline__ unsigned short f2bf(float f){
  unsigned u = __float_as_uint(f);
  u += 0x7fffu + ((u >> 16) & 1);
  return (unsigned short)(u >> 16);
}
__device__ __forceinline__ float bflo(unsigned p){ return __uint_as_float(p << 16); }
__device__ __forceinline__ float bfhi(unsigned p){ return __uint_as_float(p & 0xffff0000u); }
__device__ __forceinline__ unsigned packbf(float a, float b){
  return (unsigned)f2bf(a) | ((unsigned)f2bf(b) << 16);
}
// monotone float<->uint key for atomicMax
__device__ __forceinline__ unsigned f2key(float f){
  unsigned u = __float_as_uint(f);
  return (u & 0x80000000u) ? ~u : (u | 0x80000000u);
}
__device__ __forceinline__ float key2f(unsigned k){
  unsigned u = (k & 0x80000000u) ? (k & 0x7fffffffu) : ~k;
  return __uint_as_float(u);
}

struct SrcPtrs { const void* p[12]; };
// Weight conversion (blocks 0-11: f32 copies; block 0 publishes flag)
// + MFMA fragmentation (blocks 12-15): W -> hi/lo bf16 in lane order
// + zero blocks (16-23): clear SKA + bcur (replaces hipMemsetAsync dispatch)
__global__ void k_cvtall(SrcPtrs sp, float* __restrict__ Wc,
                         unsigned short* __restrict__ Wf, int* __restrict__ flag,
                         unsigned* __restrict__ zero0){
  const int sz[12]  = {8192,64,4096,64,8192,128,128,128,8192,64,64,32};
  const int off[12] = {0,8192,8256,12352,12416,20608,20736,20864,20992,29184,29248,29312};
  int tid = threadIdx.x;
  int b = blockIdx.x;
  if(b >= 16){
    constexpr int ZN = 128 + NPART*NNB*16;   // SKA + bcur dwords
    for(int i = (b-16)*256 + tid; i < ZN; i += 8*256) zero0[i] = 0u;
    return;
  }
  __shared__ int bad;
  if(tid == 0) bad = 0;
  __syncthreads();
  const unsigned short* q = (const unsigned short*)sp.p[0];   // W1, >=16KB either dtype
  int local = 0;
  for(int i = tid; i < 8192; i += 256){
    int e = (q[i] >> 7) & 0xFF;
    if(e >= 0xC0) local = 1;
  }
  if(local) atomicOr(&bad, 1);
  __syncthreads();
  int f = bad;
  if(b == 0 && tid == 0) *flag = f;
  if(b < 12){
    const void* src = sp.p[b];
    float* dst = Wc + off[b];
    int n = sz[b];
    for(int i = tid; i < n; i += 256) dst[i] = cvt(src, i, f);
  } else {
    int g = b - 12;
    const int KK[4]   = {128, 64, 64, 128};
    const int NNo[4]  = {64, 64, 128, 64};
    const int srcI[4] = {0, 2, 4, 8};            // W1, W2, Wg1, Wg2 in sp.p
    const int foff[4] = {0, 16384, 24576, 40960};
    int K = KK[g], N = NNo[g], KF = K/32;
    const void* src = sp.p[srcI[g]];
    unsigned short* dh = Wf + foff[g];
    unsigned short* dl = dh + K*N;
    int tot = K*N;
    for(int idx = tid; idx < tot; idx += 256){
      int i = idx & 7, lane = (idx >> 3) & 63, fr = idx >> 9;
      int kf = fr % KF, nf = fr / KF;
      int k = kf*32 + ((lane >> 4) << 3) + i;
      int n = nf*16 + (lane & 15);
      float w = cvt(src, (long long)k*N + n, f);
      unsigned short h = f2bf(w);
      dh[idx] = h;
      dl[idx] = f2bf(w - __uint_as_float((unsigned)h << 16));
    }
  }
}

// ---------------- CSR build ----------------
// k_bin (LDS-staged counting sort): per block of 1024 edges, LDS histogram over
// 391 buckets -> ONE global atomicAdd per (bucket, block) (<=391 vs 1024) ->
// LDS-sorted staging -> coalesced run-writes per bucket. Bucket id packed into
// payload bits [23:31], stripped on store. Order within a (bucket,partition)
// region changes vs the atomic-race order — both are nondeterministic; scatter
// is order-agnostic.
__global__ void k_bin(const int* __restrict__ ei, int* __restrict__ bcur,
                      unsigned* __restrict__ tmp){
  __shared__ int hist[NNB];
  __shared__ int sc[2][512];
  __shared__ int loffs[NNB];
  __shared__ int base[NNB];
  __shared__ int cur[NNB];
  __shared__ unsigned sorted[BINB];
  int tid = threadIdx.x;
  int p = blockIdx.x & (NPART-1);
  int e0 = blockIdx.x * BINB;
  for(int i = tid; i < NNB; i += 256) hist[i] = 0;
  __syncthreads();
  unsigned pay[4]; int bb[4];
#pragma unroll
  for(int k = 0; k < 4; k++){
    int e = e0 + k*256 + tid;
    bb[k] = -1;
    if(e < NE){
      int dst = ei[NE + e], src = ei[e];
      int b = dst >> 7;
      bb[k] = b;
      pay[k] = (unsigned)src | ((unsigned)(dst & 127) << 16) | ((unsigned)b << 23);
      atomicAdd(&hist[b], 1);
    }
  }
  __syncthreads();
  // inclusive scan of hist over 512 slots (2 slots/thread)
  for(int i = tid; i < 512; i += 256) sc[0][i] = (i < NNB) ? hist[i] : 0;
  __syncthreads();
  int cs = 0;
  for(int off = 1; off < 512; off <<= 1){
    int nx = cs^1;
    for(int i = tid; i < 512; i += 256){
      int v = sc[cs][i];
      if(i >= off) v += sc[cs][i-off];
      sc[nx][i] = v;
    }
    __syncthreads();
    cs = nx;
  }
  for(int b = tid; b < NNB; b += 256){
    int h = hist[b];
    int lo = sc[cs][b] - h;
    loffs[b] = lo;
    cur[b] = lo;
    base[b] = h ? atomicAdd(&bcur[(p*NNB + b)*16], h) : 0;
  }
  __syncthreads();
#pragma unroll
  for(int k = 0; k < 4; k++){
    if(bb[k] >= 0){
      int li = atomicAdd(&cur[bb[k]], 1);
      sorted[li] = pay[k];
    }
  }
  __syncthreads();
  int tot = sc[cs][NNB-1];
  for(int i = tid; i < tot; i += 256){
    unsigned v = sorted[i];
    int b = v >> 23;
    int gpos = base[b] + (i - loffs[b]);
    if(gpos < PCAP)
      tmp[((size_t)(b*NPART + p) << 9) + gpos] = v & 0x7FFFFFu;
  }
}

__global__ void k_scatter(const int* __restrict__ bcur,
                          const unsigned* __restrict__ tmp, int* __restrict__ rowptr,
                          int* __restrict__ rowend, float* __restrict__ dinv,
                          unsigned short* __restrict__ srcidx16){
  __shared__ int hist[128];
  __shared__ int lcur[128];
  __shared__ int sh[2][128];
  __shared__ int red[256];
  int b = blockIdx.x;
  int dst0 = b << 7;
  int nd = min(128, NN - dst0);
  int tid = threadIdx.x;
  int partial = 0;
  for(int i = tid; i < b*NPART; i += 256){
    int b2 = i >> 3, p = i & 7;
    partial += bcur[(p*NNB + b2)*16];
  }
  red[tid] = partial;
  if(tid < 128) hist[tid] = 0;
  __syncthreads();
  for(int off = 128; off; off >>= 1){
    if(tid < off) red[tid] += red[tid + off];
    __syncthreads();
  }
  int base = red[0] + (b << 7);
  for(int p = 0; p < NPART; p++){
    int cnt = min(bcur[(p*NNB + b)*16], PCAP);
    const unsigned* tp = tmp + ((size_t)(b*NPART + p) << 9);
    for(int i = tid; i < cnt; i += 256) atomicAdd(&hist[tp[i] >> 16], 1);
  }
  __syncthreads();
  int c = (tid < 128) ? hist[tid] + 1 : 0;     // +1 self loop
  if(tid < 128) sh[0][tid] = c;
  __syncthreads();
  int cur = 0;
  for(int off = 1; off < 128; off <<= 1){
    int nxt = cur^1;
    if(tid < 128){
      int v = sh[cur][tid];
      if(tid >= off) v += sh[cur][tid-off];
      sh[nxt][tid] = v;
    }
    __syncthreads();
    cur = nxt;
  }
  if(tid < nd){
    int rp = base + sh[cur][tid] - c;
    int d = dst0 + tid;
    rowptr[d] = rp;
    srcidx16[rp] = (unsigned short)d;
    rowend[d] = rp + c;
    dinv[d] = rsqrtf((float)c);
    lcur[tid] = rp + 1;
  }
  __syncthreads();
  for(int p = 0; p < NPART; p++){
    int cnt = min(bcur[(p*NNB + b)*16], PCAP);
    const unsigned* tp = tmp + ((size_t)(b*NNB*0 + b*NPART + p) << 9);
    for(int i = tid; i < cnt; i += 256){
      unsigned v = tp[i];
      int pos = atomicAdd(&lcur[v >> 16], 1);
      srcidx16[pos] = (unsigned short)(v & 0xffffu);
    }
  }
}

// ---------------- MFMA dense layers ----------------
template<int KIN, int KOUT, bool SCALE, int PACKC, int MODE>
__global__ void k_mfma(const void* __restrict__ X, const unsigned short* __restrict__ Wh,
                       const unsigned short* __restrict__ Wl,
                       const float* __restrict__ dinv, void* __restrict__ out,
                       const float* __restrict__ asrc, const float* __restrict__ adst,
                       float* __restrict__ sS, float* __restrict__ sD,
                       unsigned* __restrict__ ska, const int* __restrict__ flag){
  constexpr int KF = KIN/32;
  constexpr int NF = KOUT/16;
  constexpr int PITCH = KOUT + 1;
  __shared__ float Cl[64*PITCH];
  __shared__ unsigned skey[2];
  int tid = threadIdx.x;
  if(PACKC > 0 && tid < 2) skey[tid] = 0;
  int wv = tid >> 6, lane = tid & 63;
  int lr = lane >> 4, lc = lane & 15;
  int row0 = blockIdx.x*64;
  int arow = row0 + wv*16 + lc;
  if(arow >= NN) arow = NN - 1;                  // clamp: results discarded
  int f = (MODE == 1) ? *flag : 0;
  const char* xb = (const char*)X;
  f32x4 acc[NF];
#pragma unroll
  for(int nf = 0; nf < NF; nf++) acc[nf] = (f32x4){0.f,0.f,0.f,0.f};
#pragma unroll
  for(int kf = 0; kf < KF; kf++){
    bf16x8 a;
    if(MODE == 1 && f){
      const float* xf = (const float*)xb + (size_t)arow*KIN + kf*32 + lr*8;
      float4 u = *(const float4*)xf;
      float4 v = *(const float4*)(xf + 4);
      a[0]=(short)f2bf(u.x); a[1]=(short)f2bf(u.y); a[2]=(short)f2bf(u.z); a[3]=(short)f2bf(u.w);
      a[4]=(short)f2bf(v.x); a[5]=(short)f2bf(v.y); a[6]=(short)f2bf(v.z); a[7]=(short)f2bf(v.w);
    } else {
      a = *(const bf16x8*)(xb + (size_t)arow*(KIN*2) + kf*64 + lr*16);
    }
#pragma unroll
    for(int nf = 0; nf < NF; nf++){
      int fr = nf*KF + kf;
      bf16x8 wh = *(const bf16x8*)((const short*)Wh + (fr << 9) + (lane << 3));
      bf16x8 wl = *(const bf16x8*)((const short*)Wl + (fr << 9) + (lane << 3));
      acc[nf] = __builtin_amdgcn_mfma_f32_16x16x32_bf16(a, wh, acc[nf], 0, 0, 0);
      acc[nf] = __builtin_amdgcn_mfma_f32_16x16x32_bf16(a, wl, acc[nf], 0, 0, 0);
    }
  }
#pragma unroll
  for(int nf = 0; nf < NF; nf++)
#pragma unroll
    for(int r = 0; r < 4; r++)
      Cl[(wv*16 + lr*4 + r)*PITCH + nf*16 + lc] = acc[nf][r];
  __syncthreads();
  int row = tid >> 2, q = tid & 3;
  int grow = row0 + row;
  bool valid = grow < NN;
  const float* cr = &Cl[row*PITCH];
  if constexpr (PACKC == 0){
    float s = SCALE ? (valid ? dinv[grow] : 0.0f) : 1.0f;
    unsigned ov[8];
#pragma unroll
    for(int j = 0; j < 8; j++)
      ov[j] = packbf(cr[q*16 + 2*j]*s, cr[q*16 + 2*j + 1]*s);
    if(valid){
      unsigned* op = (unsigned*)out + (size_t)grow*(KOUT/2) + q*8;
      *(uint4*)op       = make_uint4(ov[0],ov[1],ov[2],ov[3]);
      *(uint4*)(op + 4) = make_uint4(ov[4],ov[5],ov[6],ov[7]);
    }
  } else {
    constexpr int C = PACKC;
    constexpr int CT = C/4;                     // cols per thread
    float s0=0.f, d0=0.f, s1=0.f, d1=0.f;
    unsigned ov[CT];
#pragma unroll
    for(int j = 0; j < CT; j++){
      int c = q*CT + j;
      float a = cr[c], bb = cr[C + c];
      ov[j] = packbf(a, bb);
      s0 += a*asrc[c];      d0 += a*adst[c];
      s1 += bb*asrc[C + c]; d1 += bb*adst[C + c];
    }
    if(valid){
      unsigned* op = (unsigned*)out + (size_t)grow*C + q*CT;
#pragma unroll
      for(int j4 = 0; j4 < CT/4; j4++)
        *(uint4*)(op + 4*j4) = make_uint4(ov[4*j4],ov[4*j4+1],ov[4*j4+2],ov[4*j4+3]);
    }
    s0 += __shfl_xor(s0,1); s0 += __shfl_xor(s0,2);
    d0 += __shfl_xor(d0,1); d0 += __shfl_xor(d0,2);
    s1 += __shfl_xor(s1,1); s1 += __shfl_xor(s1,2);
    d1 += __shfl_xor(d1,1); d1 += __shfl_xor(d1,2);
    if(valid && q == 0){
      *(float2*)(sS + 2*grow) = make_float2(s0, s1);
      *(float2*)(sD + 2*grow) = make_float2(d0, d1);
      atomicMax(&skey[0], f2key(s0));
      atomicMax(&skey[1], f2key(s1));
    }
    __syncthreads();
    if(tid < 2) atomicMax(&ska[tid*32 + (blockIdx.x & 31)], skey[tid]);
  }
}

// ---------------- gather aggregations (unchanged from R7) ----------------
// GCN: 4 nodes per wave; 8 lanes/edge; LDS meta scratchpad.
__global__ void k_gcn_gather(const int* __restrict__ rowptr, const int* __restrict__ rowend,
                             const unsigned short* __restrict__ srcidx16, const float* __restrict__ dinv,
                             const unsigned* __restrict__ Au32, const float* __restrict__ bias,
                             unsigned* __restrict__ B){
  __shared__ unsigned short lsrc[4][4*64];
  int wid = threadIdx.x >> 6, lane = threadIdx.x & 63;
  int n0 = (blockIdx.x*4 + wid)*4;
  if(n0 >= NN) return;
  int o = lane >> 3, c4 = lane & 7;
  unsigned short* ls = lsrc[wid];
  int s0[4], ne[4];
  float acc[4][8];
#pragma unroll
  for(int i = 0; i < 4; i++){
    int n = min(n0 + i, NN-1);
    s0[i] = rowptr[n]; ne[i] = rowend[n] - s0[i];
    if(n0 + i >= NN) ne[i] = 0;
#pragma unroll
    for(int c = 0; c < 8; c++) acc[i][c] = 0.f;
  }
#pragma unroll
  for(int i = 0; i < 4; i++){
    int e = min(lane, max(ne[i]-1, 0));
    unsigned short sv = srcidx16[s0[i] + e];
    ls[i*64 + lane] = (lane < ne[i]) ? sv : (unsigned short)0;
  }
  int itm = 0;
#pragma unroll
  for(int i = 0; i < 4; i++) itm = max(itm, (min(ne[i],64) + 7) >> 3);
#pragma unroll 2
  for(int j = 0; j < itm; j++){
    int idx = 8*j + o;
    int sb[4]; float w[4]; uint4 p[4];
#pragma unroll
    for(int i = 0; i < 4; i++){
      sb[i] = (int)ls[i*64 + idx];
      w[i] = (idx < ne[i]) ? 1.0f : 0.0f;
    }
#pragma unroll
    for(int i = 0; i < 4; i++) p[i] = *(const uint4*)(Au32 + (size_t)sb[i]*32 + c4*4);
#pragma unroll
    for(int i = 0; i < 4; i++){
      acc[i][0] += w[i]*bflo(p[i].x); acc[i][1] += w[i]*bfhi(p[i].x);
      acc[i][2] += w[i]*bflo(p[i].y); acc[i][3] += w[i]*bfhi(p[i].y);
      acc[i][4] += w[i]*bflo(p[i].z); acc[i][5] += w[i]*bfhi(p[i].z);
      acc[i][6] += w[i]*bflo(p[i].w); acc[i][7] += w[i]*bfhi(p[i].w);
    }
  }
  // rare long rows (ne > 64): global path, shuffle-based (cold)
#pragma unroll
  for(int i = 0; i < 4; i++){
    for(int base = 64; base < ne[i]; base += 64){
      int my = base + lane;
      bool v = my < ne[i];
      int s = v ? (int)srcidx16[s0[i] + my] : 0;
      float w = v ? 1.0f : 0.0f;
      int iters = (min(64, ne[i] - base) + 7) >> 3;
      for(int j = 0; j < iters; j++){
        int sb = __shfl(s, 8*j + o);
        float wb = __shfl(w, 8*j + o);
        uint4 p = *(const uint4*)(Au32 + (size_t)sb*32 + c4*4);
        acc[i][0] += wb*bflo(p.x); acc[i][1] += wb*bfhi(p.x);
        acc[i][2] += wb*bflo(p.y); acc[i][3] += wb*bfhi(p.y);
        acc[i][4] += wb*bflo(p.z); acc[i][5] += wb*bfhi(p.z);
        acc[i][6] += wb*bflo(p.w); acc[i][7] += wb*bfhi(p.w);
      }
    }
  }
#pragma unroll
  for(int i = 0; i < 4; i++)
#pragma unroll
    for(int off = 8; off <= 32; off <<= 1){
      acc[i][0] += __shfl_xor(acc[i][0], off); acc[i][1] += __shfl_xor(acc[i][1], off);
      acc[i][2] += __shfl_xor(acc[i][2], off); acc[i][3] += __shfl_xor(acc[i][3], off);
      acc[i][4] += __shfl_xor(acc[i][4], off); acc[i][5] += __shfl_xor(acc[i][5], off);
      acc[i][6] += __shfl_xor(acc[i][6], off); acc[i][7] += __shfl_xor(acc[i][7], off);
    }
  if(o == 0){
    int cb = 8*c4;
#pragma unroll
    for(int i = 0; i < 4; i++){
      int n = n0 + i;
      if(n >= NN) break;
      float dn = dinv[n];
      uint4 r;
      r.x = packbf(fmaxf(acc[i][0]*dn + bias[cb+0], 0.0f), fmaxf(acc[i][1]*dn + bias[cb+1], 0.0f));
      r.y = packbf(fmaxf(acc[i][2]*dn + bias[cb+2], 0.0f), fmaxf(acc[i][3]*dn + bias[cb+3], 0.0f));
      r.z = packbf(fmaxf(acc[i][4]*dn + bias[cb+4], 0.0f), fmaxf(acc[i][5]*dn + bias[cb+5], 0.0f));
      r.w = packbf(fmaxf(acc[i][6]*dn + bias[cb+6], 0.0f), fmaxf(acc[i][7]*dn + bias[cb+7], 0.0f));
      *(uint4*)(B + (size_t)n*32 + c4*4) = r;
    }
  }
}

// per-wave reduction of the 32-slot spread max keys
__device__ __forceinline__ void ska_max2(const unsigned* __restrict__ ska, int lane,
                                         float& m0, float& m1){
  unsigned kk = ska[lane];
#pragma unroll
  for(int off = 1; off <= 16; off <<= 1) kk = max(kk, __shfl_xor(kk, off));
  m0 = key2f(__shfl(kk, 0));
  m1 = key2f(__shfl(kk, 32));
}

// GAT1 (heads=2, C=64, concat): 2 nodes per wave; 16 lanes/edge; LDS meta.
__global__ void k_gat1_gather(const int* __restrict__ rowptr, const int* __restrict__ rowend,
                              const unsigned short* __restrict__ srcidx16, const float* __restrict__ sS,
                              const float* __restrict__ sD, const unsigned* __restrict__ Ab,
                              const float* __restrict__ bias, unsigned* __restrict__ B,
                              const unsigned* __restrict__ ska){
  __shared__ unsigned short lsrc[4][2*64];
  __shared__ float lw0[4][2*64];
  __shared__ float lw1[4][2*64];
  int wid = threadIdx.x >> 6, lane = threadIdx.x & 63;
  int n0 = (blockIdx.x*4 + wid)*2;
  if(n0 >= NN) return;
  float g0, g1;
  ska_max2(ska, lane, g0, g1);
  int q = lane >> 4, c4 = lane & 15;
  int s0[2], ne[2];
  float d0[2], d1[2], m0[2], m1[2];
  float z0[2] = {0.f,0.f}, z1[2] = {0.f,0.f};
  float ab[2][4], ac[2][4];
#pragma unroll
  for(int i = 0; i < 2; i++){
    int n = min(n0 + i, NN-1);
    s0[i] = rowptr[n]; ne[i] = rowend[n] - s0[i];
    if(n0 + i >= NN) ne[i] = 0;
    d0[i] = sD[n*2]; d1[i] = sD[n*2+1];
    float t0 = g0 + d0[i];  m0[i] = t0 > 0.0f ? t0 : 0.2f*t0;
    float t1 = g1 + d1[i];  m1[i] = t1 > 0.0f ? t1 : 0.2f*t1;
#pragma unroll
    for(int c = 0; c < 4; c++){ ab[i][c] = 0.f; ac[i][c] = 0.f; }
  }
#pragma unroll
  for(int i = 0; i < 2; i++){
    int e = min(lane, max(ne[i]-1, 0));
    int src = (int)srcidx16[s0[i] + e];
    bool v = lane < ne[i];
    float2 sv = *(const float2*)(sS + src*2);
    float e0 = sv.x + d0[i]; e0 = e0 > 0.0f ? e0 : 0.2f*e0;
    float e1 = sv.y + d1[i]; e1 = e1 > 0.0f ? e1 : 0.2f*e1;
    float w0v = v ? __expf(e0 - m0[i]) : 0.0f;
    float w1v = v ? __expf(e1 - m1[i]) : 0.0f;
    z0[i] += w0v; z1[i] += w1v;
    lsrc[wid][i*64 + lane] = (unsigned short)(v ? src : 0);
    lw0[wid][i*64 + lane] = w0v;
    lw1[wid][i*64 + lane] = w1v;
  }
  {
    int it0 = (min(ne[0],64) + 3) >> 2, it1 = (min(ne[1],64) + 3) >> 2;
    int itm = max(it0, it1);
#pragma unroll 4
    for(int j = 0; j < itm; j++){
      int idx = 4*j + q;
      int sb0 = (int)lsrc[wid][idx];
      float f00 = lw0[wid][idx], f01 = lw1[wid][idx];
      int sb1 = (int)lsrc[wid][64 + idx];
      float f10 = lw0[wid][64 + idx], f11 = lw1[wid][64 + idx];
      uint4 pa = *(const uint4*)(Ab + (size_t)sb0*64 + c4*4);
      uint4 pb = *(const uint4*)(Ab + (size_t)sb1*64 + c4*4);
      ab[0][0] += bflo(pa.x)*f00; ac[0][0] += bfhi(pa.x)*f01;
      ab[0][1] += bflo(pa.y)*f00; ac[0][1] += bfhi(pa.y)*f01;
      ab[0][2] += bflo(pa.z)*f00; ac[0][2] += bfhi(pa.z)*f01;
      ab[0][3] += bflo(pa.w)*f00; ac[0][3] += bfhi(pa.w)*f01;
      ab[1][0] += bflo(pb.x)*f10; ac[1][0] += bfhi(pb.x)*f11;
      ab[1][1] += bflo(pb.y)*f10; ac[1][1] += bfhi(pb.y)*f11;
      ab[1][2] += bflo(pb.z)*f10; ac[1][2] += bfhi(pb.z)*f11;
      ab[1][3] += bflo(pb.w)*f10; ac[1][3] += bfhi(pb.w)*f11;
    }
  }
  // rare long rows: global shuffle path (cold)
#pragma unroll
  for(int i = 0; i < 2; i++){
    for(int base = 64; base < ne[i]; base += 64){
      int my = base + lane;
      int s = 0; float u0 = 0.f, u1 = 0.f;
      if(my < ne[i]){
        s = (int)srcidx16[s0[i] + my];
        float2 sv = *(const float2*)(sS + s*2);
        float e0 = sv.x + d0[i]; e0 = e0 > 0.0f ? e0 : 0.2f*e0;
        float e1 = sv.y + d1[i]; e1 = e1 > 0.0f ? e1 : 0.2f*e1;
        u0 = __expf(e0 - m0[i]); u1 = __expf(e1 - m1[i]);
        z0[i] += u0; z1[i] += u1;
      }
      int iters = (min(64, ne[i] - base) + 3) >> 2;
      for(int j = 0; j < iters; j++){
        int idx = 4*j + q;
        int sb = __shfl(s, idx);
        float a0 = __shfl(u0, idx), a1 = __shfl(u1, idx);
        uint4 p = *(const uint4*)(Ab + (size_t)sb*64 + c4*4);
        ab[i][0] += bflo(p.x)*a0; ac[i][0] += bfhi(p.x)*a1;
        ab[i][1] += bflo(p.y)*a0; ac[i][1] += bfhi(p.y)*a1;
        ab[i][2] += bflo(p.z)*a0; ac[i][2] += bfhi(p.z)*a1;
        ab[i][3] += bflo(p.w)*a0; ac[i][3] += bfhi(p.w)*a1;
      }
    }
  }
#pragma unroll
  for(int i = 0; i < 2; i++){
#pragma unroll
    for(int off = 1; off <= 32; off <<= 1){ z0[i] += __shfl_xor(z0[i], off); z1[i] += __shfl_xor(z1[i], off); }
#pragma unroll
    for(int off = 16; off <= 32; off <<= 1){
      ab[i][0] += __shfl_xor(ab[i][0], off); ab[i][1] += __shfl_xor(ab[i][1], off);
      ab[i][2] += __shfl_xor(ab[i][2], off); ab[i][3] += __shfl_xor(ab[i][3], off);
      ac[i][0] += __shfl_xor(ac[i][0], off); ac[i][1] += __shfl_xor(ac[i][1], off);
      ac[i][2] += __shfl_xor(ac[i][2], off); ac[i][3] += __shfl_xor(ac[i][3], off);
    }
  }
  if(q == 0){
    int cb = 4*c4;
#pragma unroll
    for(int i = 0; i < 2; i++){
      int n = n0 + i;
      if(n >= NN) break;
      float iz0 = 1.0f/(z0[i] + 1e-16f), iz1 = 1.0f/(z1[i] + 1e-16f);
      uint2 r0, r1;
      r0.x = packbf(fmaxf(ab[i][0]*iz0 + bias[cb+0], 0.0f), fmaxf(ab[i][1]*iz0 + bias[cb+1], 0.0f));
      r0.y = packbf(fmaxf(ab[i][2]*iz0 + bias[cb+2], 0.0f), fmaxf(ab[i][3]*iz0 + bias[cb+3], 0.0f));
      r1.x = packbf(fmaxf(ac[i][0]*iz1 + bias[64+cb+0], 0.0f), fmaxf(ac[i][1]*iz1 + bias[64+cb+1], 0.0f));
      r1.y = packbf(fmaxf(ac[i][2]*iz1 + bias[64+cb+2], 0.0f), fmaxf(ac[i][3]*iz1 + bias[64+cb+3], 0.0f));
      *(uint2*)(B + (size_t)n*64 + 2*c4)      = r0;
      *(uint2*)(B + (size_t)n*64 + 32 + 2*c4) = r1;
    }
  }
}

// GAT2 (heads=2, C=32, mean) + bias + log_softmax: 2 nodes per wave; 8 lanes/edge; LDS meta.
__global__ void k_gat2_final(const int* __restrict__ rowptr, const int* __restrict__ rowend,
                             const unsigned short* __restrict__ srcidx16, const float* __restrict__ sS,
                             const float* __restrict__ sD, const unsigned* __restrict__ Ab,
                             const float* __restrict__ bias, void* __restrict__ out,
                             const int* __restrict__ flag, const unsigned* __restrict__ ska){
  __shared__ unsigned short lsrc[4][2*64];
  __shared__ float lw0[4][2*64];
  __shared__ float lw1[4][2*64];
  int wid = threadIdx.x >> 6, lane = threadIdx.x & 63;
  int n0 = (blockIdx.x*4 + wid)*2;
  if(n0 >= NN) return;
  float g0, g1;
  ska_max2(ska, lane, g0, g1);
  int o = lane >> 3, c4 = lane & 7;
  int s0[2], ne[2];
  float d0[2], d1[2], m0[2], m1[2];
  float z0[2] = {0.f,0.f}, z1[2] = {0.f,0.f};
  float ab[2][4], ac[2][4];
#pragma unroll
  for(int i = 0; i < 2; i++){
    int n = min(n0 + i, NN-1);
    s0[i] = rowptr[n]; ne[i] = rowend[n] - s0[i];
    if(n0 + i >= NN) ne[i] = 0;
    d0[i] = sD[n*2]; d1[i] = sD[n*2+1];
    float t0 = g0 + d0[i];  m0[i] = t0 > 0.0f ? t0 : 0.2f*t0;
    float t1 = g1 + d1[i];  m1[i] = t1 > 0.0f ? t1 : 0.2f*t1;
#pragma unroll
    for(int c = 0; c < 4; c++){ ab[i][c] = 0.f; ac[i][c] = 0.f; }
  }
#pragma unroll
  for(int i = 0; i < 2; i++){
    int e = min(lane, max(ne[i]-1, 0));
    int src = (int)srcidx16[s0[i] + e];
    bool v = lane < ne[i];
    float2 sv = *(const float2*)(sS + src*2);
    float e0 = sv.x + d0[i]; e0 = e0 > 0.0f ? e0 : 0.2f*e0;
    float e1 = sv.y + d1[i]; e1 = e1 > 0.0f ? e1 : 0.2f*e1;
    float w0v = v ? __expf(e0 - m0[i]) : 0.0f;
    float w1v = v ? __expf(e1 - m1[i]) : 0.0f;
    z0[i] += w0v; z1[i] += w1v;
    lsrc[wid][i*64 + lane] = (unsigned short)(v ? src : 0);
    lw0[wid][i*64 + lane] = w0v;
    lw1[wid][i*64 + lane] = w1v;
  }
  {
    int it0 = (min(ne[0],64) + 7) >> 3, it1 = (min(ne[1],64) + 7) >> 3;
    int itm = max(it0, it1);
#pragma unroll 4
    for(int j = 0; j < itm; j++){
      int idx = 8*j + o;
      int sb0 = (int)lsrc[wid][idx];
      float f00 = lw0[wid][idx], f01 = lw1[wid][idx];
      int sb1 = (int)lsrc[wid][64 + idx];
      float f10 = lw0[wid][64 + idx], f11 = lw1[wid][64 + idx];
      uint4 pa = *(const uint4*)(Ab + (size_t)sb0*32 + c4*4);
      uint4 pb = *(const uint4*)(Ab + (size_t)sb1*32 + c4*4);
      ab[0][0] += bflo(pa.x)*f00; ac[0][0] += bfhi(pa.x)*f01;
      ab[0][1] += bflo(pa.y)*f00; ac[0][1] += bfhi(pa.y)*f01;
      ab[0][2] += bflo(pa.z)*f00; ac[0][2] += bfhi(pa.z)*f01;
      ab[0][3] += bflo(pa.w)*f00; ac[0][3] += bfhi(pa.w)*f01;
      ab[1][0] += bflo(pb.x)*f10; ac[1][0] += bfhi(pb.x)*f11;
      ab[1][1] += bflo(pb.y)*f10; ac[1][1] += bfhi(pb.y)*f11;
      ab[1][2] += bflo(pb.z)*f10; ac[1][2] += bfhi(pb.z)*f11;
      ab[1][3] += bflo(pb.w)*f10; ac[1][3] += bfhi(pb.w)*f11;
    }
  }
  // rare long rows: global shuffle path (cold)
#pragma unroll
  for(int i = 0; i < 2; i++){
    for(int base = 64; base < ne[i]; base += 64){
      int my = base + lane;
      int s = 0; float u0 = 0.f, u1 = 0.f;
      if(my < ne[i]){
        s = (int)srcidx16[s0[i] + my];
        float2 sv = *(const float2*)(sS + s*2);
        float e0 = sv.x + d0[i]; e0 = e0 > 0.0f ? e0 : 0.2f*e0;
        float e1 = sv.y + d1[i]; e1 = e1 > 0.0f ? e1 : 0.2f*e1;
        u0 = __expf(e0 - m0[i]); u1 = __expf(e1 - m1[i]);
        z0[i] += u0; z1[i] += u1;
      }
      int iters = (min(64, ne[i] - base) + 7) >> 3;
      for(int j = 0; j < iters; j++){
        int idx = 8*j + o;
        int sb = __shfl(s, idx);
        float a0 = __shfl(u0, idx), a1 = __shfl(u1, idx);
        uint4 p = *(const uint4*)(Ab + (size_t)sb*32 + c4*4);
        ab[i][0] += bflo(p.x)*a0; ac[i][0] += bfhi(p.x)*a1;
        ab[i][1] += bflo(p.y)*a0; ac[i][1] += bfhi(p.y)*a1;
        ab[i][2] += bflo(p.z)*a0; ac[i][2] += bfhi(p.z)*a1;
        ab[i][3] += bflo(p.w)*a0; ac[i][3] += bfhi(p.w)*a1;
      }
    }
  }
  int fl = *flag;
#pragma unroll
  for(int i = 0; i < 2; i++){
#pragma unroll
    for(int off = 1; off <= 32; off <<= 1){ z0[i] += __shfl_xor(z0[i], off); z1[i] += __shfl_xor(z1[i], off); }
#pragma unroll
    for(int off = 8; off <= 32; off <<= 1){
      ab[i][0] += __shfl_xor(ab[i][0], off); ab[i][1] += __shfl_xor(ab[i][1], off);
      ab[i][2] += __shfl_xor(ab[i][2], off); ab[i][3] += __shfl_xor(ab[i][3], off);
      ac[i][0] += __shfl_xor(ac[i][0], off); ac[i][1] += __shfl_xor(ac[i][1], off);
      ac[i][2] += __shfl_xor(ac[i][2], off); ac[i][3] += __shfl_xor(ac[i][3], off);
    }
    int n = n0 + i;
    if(n >= NN) continue;
    float iz0 = 1.0f/(z0[i] + 1e-16f), iz1 = 1.0f/(z1[i] + 1e-16f);
    int cb = 4*c4;
    float o0 = 0.5f*(ab[i][0]*iz0 + ac[i][0]*iz1) + bias[cb+0];
    float o1 = 0.5f*(ab[i][1]*iz0 + ac[i][1]*iz1) + bias[cb+1];
    float o2 = 0.5f*(ab[i][2]*iz0 + ac[i][2]*iz1) + bias[cb+2];
    float o3 = 0.5f*(ab[i][3]*iz0 + ac[i][3]*iz1) + bias[cb+3];
    float mx = fmaxf(fmaxf(o0, o1), fmaxf(o2, o3));
    for(int off = 4; off; off >>= 1) mx = fmaxf(mx, __shfl_xor(mx, off));
    float sm = __expf(o0 - mx) + __expf(o1 - mx) + __expf(o2 - mx) + __expf(o3 - mx);
    for(int off = 4; off; off >>= 1) sm += __shfl_xor(sm, off);
    float lse = mx + __logf(sm);
    if(o == 0){
      if(fl){
        float4 r;
        r.x = o0 - lse; r.y = o1 - lse; r.z = o2 - lse; r.w = o3 - lse;
        *(float4*)((float*)out + (size_t)n*32 + cb) = r;
      } else {
        uint2 r;
        r.x = packbf(o0 - lse, o1 - lse);
        r.y = packbf(o2 - lse, o3 - lse);
        *(uint2*)((unsigned*)out + (size_t)n*16 + 2*c4) = r;
      }
    }
  }
}

extern "C" void kernel_launch(void* const* d_in, const int* in_sizes, int n_in,
                              void* d_out, int out_size, void* d_ws, size_t ws_size,
                              hipStream_t stream) {
  const void* x   = d_in[0];
  const int*  ei  = (const int*)d_in[1];

  float* A    = (float*)d_ws;
  unsigned short* Au = (unsigned short*)A;
  unsigned* Au32 = (unsigned*)A;
  unsigned* Ab = (unsigned*)(A + (size_t)NN*64);   // +12.8MB
  float* B    = A + (size_t)NN*128;
  float* dinv = B + (size_t)NN*128;
  float* sS   = dinv + NN;
  float* sD   = sS + 2*NN;
  int* rowptr = (int*)(sD + 2*NN);
  int* rowend = rowptr + NN;
  unsigned short* srcidx16 = (unsigned short*)(rowend + NN);
  unsigned* SKA = (unsigned*)(srcidx16 + NT + 2);  // [2 gats][2 heads][32 slots]
  int* bcur   = (int*)(SKA + 128);
  unsigned* tmp = (unsigned*)(bcur + NPART*NNB*16);
  float* Wc   = (float*)(tmp + (size_t)NNB*NPART*PCAP);
  int*  flag  = (int*)(Wc + 29344);
  uintptr_t wfp = ((uintptr_t)(flag + 1) + 15) & ~(uintptr_t)15;
  unsigned short* Wf = (unsigned short*)wfp;       // 57344 ushorts (hi/lo frags)

  const float* b1c  = Wc + 8192;
  const float* b2c  = Wc + 12352;
  const float* as1c = Wc + 20608;
  const float* ad1c = Wc + 20736;
  const float* bg1c = Wc + 20864;
  const float* as2c = Wc + 29184;
  const float* ad2c = Wc + 29248;
  const float* bg2c = Wc + 29312;

  dim3 g16((NN + 15)/16);       // GCN gather: 16 nodes/block (4/wave)
  dim3 g8((NN + 7)/8);          // GAT gathers: 8 nodes/block (2/wave)
  dim3 g64((NN + 63)/64);       // MFMA GEMM: 64 rows/block
  dim3 gbin((NE + BINB - 1)/BINB);

  SrcPtrs sp;
  for(int i = 0; i < 12; i++) sp.p[i] = d_in[2 + i];
  k_cvtall<<<24, 256, 0, stream>>>(sp, Wc, Wf, flag, SKA);

  k_bin<<<gbin, 256, 0, stream>>>(ei, bcur, tmp);
  k_scatter<<<NNB, 256, 0, stream>>>(bcur, tmp, rowptr, rowend, dinv, srcidx16);

  // ---- GCN1 ----
  k_mfma<128,64,true,0,1><<<g64, 256, 0, stream>>>(
      x, Wf, Wf + 8192, dinv, Au, nullptr, nullptr, nullptr, nullptr, nullptr, flag);
  k_gcn_gather<<<g16, 256, 0, stream>>>(rowptr, rowend, srcidx16, dinv, Au32, b1c, (unsigned*)B);

  // ---- GCN2 ----
  k_mfma<64,64,true,0,0><<<g64, 256, 0, stream>>>(
      B, Wf + 16384, Wf + 20480, dinv, Au, nullptr, nullptr, nullptr, nullptr, nullptr, flag);
  k_gcn_gather<<<g16, 256, 0, stream>>>(rowptr, rowend, srcidx16, dinv, Au32, b2c, (unsigned*)B);

  // ---- GAT1: heads=2, C=64, concat ----
  k_mfma<64,128,false,64,0><<<g64, 256, 0, stream>>>(
      B, Wf + 24576, Wf + 32768, dinv, Ab, as1c, ad1c, sS, sD, SKA, flag);
  k_gat1_gather<<<g8, 256, 0, stream>>>(rowptr, rowend, srcidx16, sS, sD, Ab, bg1c, (unsigned*)B, SKA);

  // ---- GAT2: heads=2, C=32, mean + log_softmax ----
  k_mfma<128,64,false,32,0><<<g64, 256, 0, stream>>>(
      B, Wf + 40960, Wf + 49152, dinv, Ab, as2c, ad2c, sS, sD, SKA + 64, flag);
  k_gat2_final<<<g8, 256, 0, stream>>>(rowptr, rowend, srcidx16, sS, sD, Ab, bg2c, d_out, flag, SKA + 64);
}